// Round 1
// baseline (80.348 us; speedup 1.0000x reference)
//
#include <hip/hip_runtime.h>
#include <hip/hip_bf16.h>
#include <math.h>

typedef unsigned long long u64;

constexpr int NB  = 8;
constexpr int NM  = 4096;
constexpr int KNN = 16;
constexpr int WPB = 4;            // waves (= queries) per block
constexpr int BLK = WPB * 64;

__device__ __forceinline__ u64 shflx64(u64 v, int m) {
  unsigned lo = (unsigned)v, hi = (unsigned)(v >> 32);
  lo = __shfl_xor(lo, m, 64);
  hi = __shfl_xor(hi, m, 64);
  return ((u64)hi << 32) | lo;
}

__global__ __launch_bounds__(BLK, 4)
void knn_eig(const float* __restrict__ X, const float* __restrict__ uv,
             float* __restrict__ out) {
  __shared__ __align__(16) float uvs[NM * 2];          // 32 KB: this batch's uv
  __shared__ u64 surv[WPB][64];                        // per-wave survivor buffer

  const int tid  = threadIdx.x;
  const int lane = tid & 63;
  const int wv   = tid >> 6;
  const int bb   = blockIdx.x >> 10;                   // 1024 blocks per batch
  const int q    = ((blockIdx.x & 1023) << 2) + wv;    // this wave's query point

  // ---- stage uv[bb] into LDS (coalesced float4) ----
  {
    const float4* g = (const float4*)(uv + (size_t)bb * NM * 2);
    float4* s = (float4*)uvs;
    #pragma unroll
    for (int i = 0; i < (NM * 2 / 4) / BLK; ++i)
      s[tid + i * BLK] = g[tid + i * BLK];
  }
  __syncthreads();

  const float qx = uvs[2 * q], qy = uvs[2 * q + 1];

  // ---- per-lane distances for candidates idx = j*64 + lane (registers only) ----
  // bit-exact vs numpy: round each sub/mul/add separately (no FMA contraction)
  float d[64];
  #pragma unroll
  for (int j = 0; j < 64; ++j) {
    const float2 c = ((const float2*)uvs)[j * 64 + lane];
    const float dx = __fsub_rn(qx, c.x);
    const float dy = __fsub_rn(qy, c.y);
    d[j] = __fadd_rn(__fmul_rn(dx, dx), __fmul_rn(dy, dy));
  }

  // ---- wave-uniform threshold search: 16 <= count(d<=hi) <= 64 ----
  float lo = 0.f, hi = 0.003f;     // analytic 16-NN radius^2 guess for 4096 uniform pts
  int chi;
  {
    int c = 0;
    #pragma unroll
    for (int j = 0; j < 64; ++j) c += (int)__popcll(__ballot(d[j] <= hi));
    chi = c;
  }
  while (chi < KNN) {              // expand (edge/corner queries)
    lo = hi; hi *= 2.f;
    int c = 0;
    #pragma unroll
    for (int j = 0; j < 64; ++j) c += (int)__popcll(__ballot(d[j] <= hi));
    chi = c;
  }
  for (int it = 0; chi > 64 && it < 64; ++it) {   // narrow
    const float mid = 0.5f * (lo + hi);
    if (!(mid > lo && mid < hi)) break;
    int c = 0;
    #pragma unroll
    for (int j = 0; j < 64; ++j) c += (int)__popcll(__ballot(d[j] <= mid));
    if (c >= KNN) { hi = mid; chi = c; } else lo = mid;
  }

  // ---- ballot-compact survivors into LDS, key = (dist_bits<<32)|idx ----
  u64* sb = surv[wv];
  int total = 0;
  #pragma unroll
  for (int j = 0; j < 64; ++j) {
    const bool p = (d[j] <= hi);
    const u64 mask = __ballot(p);
    if (p) {
      const int pos = total + (int)__popcll(mask & ((1ull << lane) - 1ull));
      if (pos < 64)
        sb[pos] = ((u64)__float_as_uint(d[j]) << 32) | (unsigned)(j * 64 + lane);
    }
    total += (int)__popcll(mask);
  }
  __syncthreads();

  // ---- wave bitonic sort of 64 keys -> lanes 0..15 hold exact top-16 ----
  const int S = total < 64 ? total : 64;
  u64 v = (lane < S) ? sb[lane] : ~0ull;
  #pragma unroll
  for (int k = 2; k <= 64; k <<= 1) {
    #pragma unroll
    for (int j = k >> 1; j > 0; j >>= 1) {
      const u64 o = shflx64(v, j);
      const bool keepmin = ((lane & j) == 0) == ((lane & k) == 0);
      const u64 mn = (v < o) ? v : o;
      const u64 mx = (v < o) ? o : v;
      v = keepmin ? mn : mx;
    }
  }

  // ---- gather X for the 16 neighbors, reduce 9 moment sums over lanes 0..15 ----
  float x = 0.f, y = 0.f, z = 0.f;
  if (lane < KNN) {
    const int idx = (int)(unsigned)v;                  // low 32 bits = candidate idx
    const float* Xp = X + ((size_t)bb * NM + idx) * 3;
    x = Xp[0]; y = Xp[1]; z = Xp[2];
  }
  float sx = x, sy = y, sz = z;
  float sxx = x * x, sxy = x * y, sxz = x * z;
  float syy = y * y, syz = y * z, szz = z * z;
  #pragma unroll
  for (int o = 8; o > 0; o >>= 1) {
    sx  += __shfl_xor(sx,  o, 64);  sy  += __shfl_xor(sy,  o, 64);
    sz  += __shfl_xor(sz,  o, 64);  sxx += __shfl_xor(sxx, o, 64);
    sxy += __shfl_xor(sxy, o, 64);  sxz += __shfl_xor(sxz, o, 64);
    syy += __shfl_xor(syy, o, 64);  syz += __shfl_xor(syz, o, 64);
    szz += __shfl_xor(szz, o, 64);
  }

  // ---- covariance (= centered^T centered, no 1/N) and closed-form eigenvalues ----
  const float mx = sx * 0.0625f, my = sy * 0.0625f, mz = sz * 0.0625f;
  const float c00 = sxx - 16.f * mx * mx;
  const float c11 = syy - 16.f * my * my;
  const float c22 = szz - 16.f * mz * mz;
  const float c01 = sxy - 16.f * mx * my;
  const float c02 = sxz - 16.f * mx * mz;
  const float c12 = syz - 16.f * my * mz;

  const float tr = c00 + c11 + c22;
  const float q3 = tr * (1.f / 3.f);
  const float b0 = c00 - q3, b1 = c11 - q3, b2 = c22 - q3;
  const float p2 = b0 * b0 + b1 * b1 + b2 * b2 +
                   2.f * (c01 * c01 + c02 * c02 + c12 * c12);
  float e0, e1, e2;
  if (p2 < 1e-30f) {
    e0 = e1 = e2 = q3;
  } else {
    const float p  = sqrtf(p2 * (1.f / 6.f));
    const float ip = 1.f / p;
    const float m00 = b0 * ip, m11 = b1 * ip, m22 = b2 * ip;
    const float m01 = c01 * ip, m02 = c02 * ip, m12 = c12 * ip;
    const float det = m00 * (m11 * m22 - m12 * m12)
                    - m01 * (m01 * m22 - m12 * m02)
                    + m02 * (m01 * m12 - m11 * m02);
    float r = 0.5f * det;
    r = fminf(1.f, fmaxf(-1.f, r));
    const float phi = acosf(r) * (1.f / 3.f);
    e0 = q3 + 2.f * p * cosf(phi);                          // largest
    e2 = q3 + 2.f * p * cosf(phi + 2.0943951023931953f);    // smallest
    e1 = tr - e0 - e2;
  }

  if (lane == 0) {
    float* op = out + ((size_t)bb * NM + q) * 3;
    op[0] = e0; op[1] = e1; op[2] = e2;                     // descending, = reversed eigvalsh
  }
}

extern "C" void kernel_launch(void* const* d_in, const int* in_sizes, int n_in,
                              void* d_out, int out_size, void* d_ws, size_t ws_size,
                              hipStream_t stream) {
  const float* X  = (const float*)d_in[0];
  const float* uv = (const float*)d_in[1];
  float* out = (float*)d_out;
  const int nblocks = NB * NM / WPB;   // 8192
  knn_eig<<<dim3(nblocks), dim3(BLK), 0, stream>>>(X, uv, out);
}

// Round 2
// 69.299 us; speedup vs baseline: 1.1594x; 1.1594x over previous
//
#include <hip/hip_runtime.h>
#include <hip/hip_bf16.h>
#include <math.h>

typedef unsigned long long u64;

constexpr int NB  = 8;
constexpr int NM  = 4096;
constexpr int KNN = 16;
constexpr int WPB = 8;            // waves (= queries) per block
constexpr int BLK = WPB * 64;     // 512 threads

__device__ __forceinline__ u64 shflx64(u64 v, int m) {
  unsigned lo = (unsigned)v, hi = (unsigned)(v >> 32);
  lo = __shfl_xor(lo, m, 64);
  hi = __shfl_xor(hi, m, 64);
  return ((u64)hi << 32) | lo;
}

__device__ __forceinline__ int wave_sum(int c) {
  #pragma unroll
  for (int o = 32; o > 0; o >>= 1) c += __shfl_xor(c, o, 64);
  return c;
}

__global__ __launch_bounds__(BLK, 4)
void knn_eig(const float* __restrict__ X, const float* __restrict__ uv,
             float* __restrict__ out) {
  __shared__ __align__(16) float uvs[NM * 2];          // 32 KB: this batch's uv
  __shared__ u64 surv[WPB][64];                        // per-wave survivor buffer (4 KB)

  const int tid  = threadIdx.x;
  const int lane = tid & 63;
  const int wv   = tid >> 6;
  const int bb   = blockIdx.x >> 9;                    // 512 blocks per batch
  const int q    = ((blockIdx.x & 511) << 3) + wv;     // this wave's query point

  // ---- stage uv[bb] into LDS (coalesced float4) ----
  {
    const float4* g = (const float4*)(uv + (size_t)bb * NM * 2);
    float4* s = (float4*)uvs;
    #pragma unroll
    for (int i = 0; i < (NM * 2 / 4) / BLK; ++i)
      s[tid + i * BLK] = g[tid + i * BLK];
  }
  __syncthreads();

  const float qx = uvs[2 * q], qy = uvs[2 * q + 1];

  // ---- distances for 64 candidates/lane (registers only), fused count at tau0 ----
  // candidate index for slot k: idx = (k>>1)*128 + 2*lane + (k&1)
  // bit-exact vs numpy: separate _rn sub/mul/add (no FMA contraction -> no set flips)
  float d[64];
  float hi = 0.003f, lo = 0.f;     // analytic 16-NN radius^2 guess, ~38 expected survivors
  int cl = 0;                      // per-lane count(d <= hi)
  {
    const float4* uv4 = (const float4*)uvs;
    #pragma unroll
    for (int j = 0; j < 32; ++j) {
      const float4 c = uv4[j * 64 + lane];
      const float dx0 = __fsub_rn(qx, c.x), dy0 = __fsub_rn(qy, c.y);
      const float dx1 = __fsub_rn(qx, c.z), dy1 = __fsub_rn(qy, c.w);
      d[2 * j]     = __fadd_rn(__fmul_rn(dx0, dx0), __fmul_rn(dy0, dy0));
      d[2 * j + 1] = __fadd_rn(__fmul_rn(dx1, dx1), __fmul_rn(dy1, dy1));
      cl += (d[2 * j] <= hi);
      cl += (d[2 * j + 1] <= hi);
    }
  }
  int chi = wave_sum(cl);

  // ---- wave-uniform threshold search: KNN <= count(d<=hi) <= 64 ----
  while (chi < KNN) {              // expand (edge/corner queries, ~21%)
    lo = hi; hi *= 2.f;
    int c = 0;
    #pragma unroll
    for (int k = 0; k < 64; ++k) c += (d[k] <= hi);
    cl = c; chi = wave_sum(c);
  }
  for (int it = 0; chi > 64 && it < 50; ++it) {   // narrow (rare at tau0)
    const float mid = 0.5f * (lo + hi);
    if (!(mid > lo && mid < hi)) break;
    int c = 0;
    #pragma unroll
    for (int k = 0; k < 64; ++k) c += (d[k] <= mid);
    const int t = wave_sum(c);
    if (t >= KNN) { hi = mid; chi = t; cl = c; } else lo = mid;
  }

  // ---- exclusive prefix scan of per-lane survivor counts -> write positions ----
  int inc = cl;
  #pragma unroll
  for (int o = 1; o < 64; o <<= 1) {
    const int t = __shfl_up(inc, o, 64);
    if (lane >= o) inc += t;
  }
  int pos = inc - cl;

  // ---- sequential per-lane compaction, key = (dist_bits<<32)|idx ----
  u64* sb = surv[wv];
  #pragma unroll
  for (int k = 0; k < 64; ++k) {
    if (d[k] <= hi) {
      if (pos < 64) {
        const unsigned idx = (unsigned)((k >> 1) * 128 + 2 * lane + (k & 1));
        sb[pos] = ((u64)__float_as_uint(d[k]) << 32) | idx;
      }
      ++pos;
    }
  }
  // surv is per-wave private: no __syncthreads needed (compiler inserts lgkmcnt)

  // ---- wave bitonic sort of 64 keys -> lanes 0..15 hold exact top-16 ----
  const int S = chi < 64 ? chi : 64;
  u64 v = (lane < S) ? sb[lane] : ~0ull;
  #pragma unroll
  for (int k = 2; k <= 64; k <<= 1) {
    #pragma unroll
    for (int j = k >> 1; j > 0; j >>= 1) {
      const u64 o = shflx64(v, j);
      const bool keepmin = ((lane & j) == 0) == ((lane & k) == 0);
      const u64 mn = (v < o) ? v : o;
      const u64 mx = (v < o) ? o : v;
      v = keepmin ? mn : mx;
    }
  }

  // ---- gather X for the 16 neighbors, reduce 9 moment sums over lanes 0..15 ----
  float x = 0.f, y = 0.f, z = 0.f;
  if (lane < KNN) {
    const int idx = (int)(unsigned)v;                  // low 32 bits = candidate idx
    const float* Xp = X + ((size_t)bb * NM + idx) * 3;
    x = Xp[0]; y = Xp[1]; z = Xp[2];
  }
  float sx = x, sy = y, sz = z;
  float sxx = x * x, sxy = x * y, sxz = x * z;
  float syy = y * y, syz = y * z, szz = z * z;
  #pragma unroll
  for (int o = 8; o > 0; o >>= 1) {
    sx  += __shfl_xor(sx,  o, 64);  sy  += __shfl_xor(sy,  o, 64);
    sz  += __shfl_xor(sz,  o, 64);  sxx += __shfl_xor(sxx, o, 64);
    sxy += __shfl_xor(sxy, o, 64);  sxz += __shfl_xor(sxz, o, 64);
    syy += __shfl_xor(syy, o, 64);  szz += __shfl_xor(szz, o, 64);
    syz += __shfl_xor(syz, o, 64);
  }

  // ---- covariance (= centered^T centered, no 1/N) and closed-form eigenvalues ----
  const float mx = sx * 0.0625f, my = sy * 0.0625f, mz = sz * 0.0625f;
  const float c00 = sxx - 16.f * mx * mx;
  const float c11 = syy - 16.f * my * my;
  const float c22 = szz - 16.f * mz * mz;
  const float c01 = sxy - 16.f * mx * my;
  const float c02 = sxz - 16.f * mx * mz;
  const float c12 = syz - 16.f * my * mz;

  const float tr = c00 + c11 + c22;
  const float q3 = tr * (1.f / 3.f);
  const float b0 = c00 - q3, b1 = c11 - q3, b2 = c22 - q3;
  const float p2 = b0 * b0 + b1 * b1 + b2 * b2 +
                   2.f * (c01 * c01 + c02 * c02 + c12 * c12);
  float e0, e1, e2;
  if (p2 < 1e-30f) {
    e0 = e1 = e2 = q3;
  } else {
    const float p  = sqrtf(p2 * (1.f / 6.f));
    const float ip = 1.f / p;
    const float m00 = b0 * ip, m11 = b1 * ip, m22 = b2 * ip;
    const float m01 = c01 * ip, m02 = c02 * ip, m12 = c12 * ip;
    const float det = m00 * (m11 * m22 - m12 * m12)
                    - m01 * (m01 * m22 - m12 * m02)
                    + m02 * (m01 * m12 - m11 * m02);
    float r = 0.5f * det;
    r = fminf(1.f, fmaxf(-1.f, r));
    const float phi = acosf(r) * (1.f / 3.f);
    e0 = q3 + 2.f * p * cosf(phi);                          // largest
    e2 = q3 + 2.f * p * cosf(phi + 2.0943951023931953f);    // smallest
    e1 = tr - e0 - e2;
  }

  if (lane == 0) {
    float* op = out + ((size_t)bb * NM + q) * 3;
    op[0] = e0; op[1] = e1; op[2] = e2;                     // descending, = reversed eigvalsh
  }
}

extern "C" void kernel_launch(void* const* d_in, const int* in_sizes, int n_in,
                              void* d_out, int out_size, void* d_ws, size_t ws_size,
                              hipStream_t stream) {
  const float* X  = (const float*)d_in[0];
  const float* uv = (const float*)d_in[1];
  float* out = (float*)d_out;
  const int nblocks = NB * NM / WPB;   // 4096
  knn_eig<<<dim3(nblocks), dim3(BLK), 0, stream>>>(X, uv, out);
}

// Round 3
// 56.910 us; speedup vs baseline: 1.4118x; 1.2177x over previous
//
#include <hip/hip_runtime.h>
#include <hip/hip_bf16.h>
#include <math.h>

typedef unsigned long long u64;
typedef unsigned int u32;
typedef unsigned short u16;

constexpr int NB  = 8;
constexpr int NM  = 4096;
constexpr int KNN = 16;
constexpr int WPB = 8;             // waves (= queries) per block
constexpr int BLK = WPB * 64;      // 512 threads
constexpr int GC  = 16;            // grid cells per dim
constexpr int NC  = GC * GC;       // 256 cells
constexpr int CSST = NC + 1;       // cellstart stride per batch
constexpr int SLOTS = 6;           // max candidates per lane (384 total)

// d_ws layout (fully rewritten every call -> poison-safe, deterministic output):
//   uvS  float2[NB][NM]   @ 0        (256 KB)  cell-ordered uv
//   idxS u16   [NB][NM]   @ 262144   ( 64 KB)  original point index
//   cs   u32   [NB][CSST] @ 327680   (  8 KB)  cell start offsets
constexpr size_t WS_UVS = 0;
constexpr size_t WS_IDX = 262144;
constexpr size_t WS_CS  = 327680;

__device__ __forceinline__ u64 shflx64(u64 v, int m) {
  unsigned lo = (unsigned)v, hi = (unsigned)(v >> 32);
  lo = __shfl_xor(lo, m, 64);
  hi = __shfl_xor(hi, m, 64);
  return ((u64)hi << 32) | lo;
}

__device__ __forceinline__ int wave_sum(int c) {
  #pragma unroll
  for (int o = 32; o > 0; o >>= 1) c += __shfl_xor(c, o, 64);
  return c;
}

// ---------------- binning: counting-sort each batch's uv into 16x16 cells ----
__global__ __launch_bounds__(512)
void bin_pts(const float* __restrict__ uv, float2* __restrict__ uvS,
             u16* __restrict__ idxS, u32* __restrict__ cs) {
  __shared__ u32 cnt[NC];
  __shared__ u32 offs[NC];
  __shared__ u32 wtot[4];
  const int bb  = blockIdx.x;
  const int tid = threadIdx.x;

  if (tid < NC) cnt[tid] = 0;
  __syncthreads();

  float2 c8[8];
  int cell[8];
  #pragma unroll
  for (int i = 0; i < 8; ++i) {
    const int p = tid + i * 512;
    const float2 c = ((const float2*)(uv + (size_t)bb * NM * 2))[p];
    int cx = (int)(c.x * (float)GC); cx = cx > GC - 1 ? GC - 1 : (cx < 0 ? 0 : cx);
    int cy = (int)(c.y * (float)GC); cy = cy > GC - 1 ? GC - 1 : (cy < 0 ? 0 : cy);
    c8[i] = c; cell[i] = cy * GC + cx;
    atomicAdd(&cnt[cell[i]], 1u);
  }
  __syncthreads();

  // exclusive scan of cnt[256] (4 full waves handle tid<256)
  if (tid < NC) {
    const int lane = tid & 63;
    u32 inc = cnt[tid];
    #pragma unroll
    for (int o = 1; o < 64; o <<= 1) {
      const u32 t = __shfl_up(inc, o, 64);
      if (lane >= o) inc += t;
    }
    offs[tid] = inc;                       // wave-inclusive
    if (lane == 63) wtot[tid >> 6] = inc;
  }
  __syncthreads();
  if (tid < NC) {
    const int w = tid >> 6;
    u32 base = 0;
    #pragma unroll
    for (int i = 0; i < 3; ++i) base += (i < w) ? wtot[i] : 0;
    const u32 excl = base + offs[tid] - cnt[tid];
    cs[bb * CSST + tid] = excl;
    offs[tid] = excl;                      // scatter counters
    if (tid == 0) cs[bb * CSST + NC] = NM;
  }
  __syncthreads();

  #pragma unroll
  for (int i = 0; i < 8; ++i) {
    const int p = tid + i * 512;
    const u32 pos = atomicAdd(&offs[cell[i]], 1u);
    uvS[(size_t)bb * NM + pos]  = c8[i];
    idxS[(size_t)bb * NM + pos] = (u16)p;
  }
}

// ---------------- main: grid-pruned exact 16-NN + covariance eigenvalues ----
__global__ __launch_bounds__(BLK, 6)
void knn_eig(const float* __restrict__ X, const float* __restrict__ uv,
             const float2* __restrict__ uvS, const u16* __restrict__ idxS,
             const u32* __restrict__ cs, float* __restrict__ out) {
  __shared__ __align__(16) float2 uvL[NM];   // 32 KB cell-ordered uv
  __shared__ __align__(16) u16 idxL[NM];     //  8 KB original indices
  __shared__ u32 csL[CSST];                  //  1 KB cell starts
  __shared__ u64 surv[WPB][64];              //  4 KB survivor buffers

  const int tid  = threadIdx.x;
  const int lane = tid & 63;
  const int wv   = tid >> 6;
  const int bb   = blockIdx.x >> 9;                 // 512 blocks per batch
  const int q    = ((blockIdx.x & 511) << 3) + wv;

  // stage per-batch tables
  {
    const float4* g = (const float4*)(uvS + (size_t)bb * NM);
    float4* s = (float4*)uvL;
    #pragma unroll
    for (int i = 0; i < 4; ++i) s[tid + i * BLK] = g[tid + i * BLK];
    ((float4*)idxL)[tid] = ((const float4*)(idxS + (size_t)bb * NM))[tid];
    if (tid < CSST) csL[tid] = cs[bb * CSST + tid];
  }
  __syncthreads();

  const float qu = uv[(size_t)bb * NM * 2 + 2 * q];
  const float qv = uv[(size_t)bb * NM * 2 + 2 * q + 1];
  int cx = (int)(qu * (float)GC); cx = cx > GC - 1 ? GC - 1 : (cx < 0 ? 0 : cx);
  int cy = (int)(qv * (float)GC); cy = cy > GC - 1 ? GC - 1 : (cy < 0 ? 0 : cy);

  // ring expansion: candidates = (2h+1)^2 cell block; guaranteed-covered radius h/16.
  // exact-kNN invariant: >=16 candidates with d <= (h/16)^2  =>  true top-16 subset of candidates.
  float d[SLOTS];
  int   ca[SLOTS];
  float tau = 0.f, lo = 0.f;
  int cl = 0, cnt = 0, total = 0;
  for (int h = 1; ; ++h) {
    const int x0 = cx - h < 0 ? 0 : cx - h, x1 = cx + h > GC - 1 ? GC - 1 : cx + h;
    const int y0 = cy - h < 0 ? 0 : cy - h, y1 = cy + h > GC - 1 ? GC - 1 : cy + h;
    int rstart[7], rcum[7];
    {
      int cum = 0;
      #pragma unroll
      for (int r = 0; r < 7; ++r) {
        const int y = y0 + r;
        const bool ok = (y <= y1);
        const u32 s = csL[ok ? (y * GC + x0) : 0];
        const u32 e = csL[ok ? (y * GC + x1 + 1) : 0];
        rstart[r] = (int)s;
        cum += ok ? (int)(e - s) : 0;
        rcum[r] = cum;
      }
      total = cum;
    }
    const float hv = (float)h * 0.0625f;
    tau = hv * hv;                                   // exact fp values
    cl = 0;
    #pragma unroll
    for (int t = 0; t < SLOTS; ++t) {
      const int L = t * 64 + lane;
      int addr = 0;
      #pragma unroll
      for (int r = 6; r >= 1; --r)
        if (L < rcum[r]) addr = rstart[r] + (L - rcum[r - 1]);
      if (L < rcum[0]) addr = rstart[0] + L;
      float dd = 1e30f;
      if (L < total) {
        const float2 c = uvL[addr];
        const float dx = __fsub_rn(qu, c.x);
        const float dy = __fsub_rn(qv, c.y);
        dd = __fadd_rn(__fmul_rn(dx, dx), __fmul_rn(dy, dy));
      }
      d[t] = dd; ca[t] = addr;
      cl += (dd <= tau);
    }
    cnt = wave_sum(cl);
    if (cnt >= KNN || h >= 5) break;
    lo = 0.f;
  }

  // narrow threshold until survivor count fits one-per-lane (rare: P(cnt>64)~2%)
  float hi2 = tau;
  lo = 0.f;
  for (int it = 0; cnt > 64 && it < 50; ++it) {
    const float mid = 0.5f * (lo + hi2);
    if (!(mid > lo && mid < hi2)) break;
    int c = 0;
    #pragma unroll
    for (int t = 0; t < SLOTS; ++t) c += (d[t] <= mid);
    const int tt = wave_sum(c);
    if (tt >= KNN) { hi2 = mid; cnt = tt; cl = c; } else lo = mid;
  }

  // compact survivors, key = (dist_bits<<32) | orig_idx (reference tie-break)
  int inc = cl;
  #pragma unroll
  for (int o = 1; o < 64; o <<= 1) {
    const int t = __shfl_up(inc, o, 64);
    if (lane >= o) inc += t;
  }
  int pos = inc - cl;
  u64* sb = surv[wv];
  #pragma unroll
  for (int t = 0; t < SLOTS; ++t) {
    if (d[t] <= hi2) {
      if (pos < 64)
        sb[pos] = ((u64)__float_as_uint(d[t]) << 32) | (u64)idxL[ca[t]];
      ++pos;
    }
  }

  // wave bitonic sort of 64 keys -> lanes 0..15 hold the exact top-16
  const int S = cnt < 64 ? cnt : 64;
  u64 v = (lane < S) ? sb[lane] : ~0ull;
  #pragma unroll
  for (int k = 2; k <= 64; k <<= 1) {
    #pragma unroll
    for (int j = k >> 1; j > 0; j >>= 1) {
      const u64 o = shflx64(v, j);
      const bool keepmin = ((lane & j) == 0) == ((lane & k) == 0);
      const u64 mn = (v < o) ? v : o;
      const u64 mx = (v < o) ? o : v;
      v = keepmin ? mn : mx;
    }
  }

  // gather X, reduce 9 moment sums over lanes 0..15
  float x = 0.f, y = 0.f, z = 0.f;
  if (lane < KNN) {
    const int idx = (int)(u32)v & 0xFFFF;
    const float* Xp = X + ((size_t)bb * NM + idx) * 3;
    x = Xp[0]; y = Xp[1]; z = Xp[2];
  }
  float sx = x, sy = y, sz = z;
  float sxx = x * x, sxy = x * y, sxz = x * z;
  float syy = y * y, syz = y * z, szz = z * z;
  #pragma unroll
  for (int o = 8; o > 0; o >>= 1) {
    sx  += __shfl_xor(sx,  o, 64);  sy  += __shfl_xor(sy,  o, 64);
    sz  += __shfl_xor(sz,  o, 64);  sxx += __shfl_xor(sxx, o, 64);
    sxy += __shfl_xor(sxy, o, 64);  sxz += __shfl_xor(sxz, o, 64);
    syy += __shfl_xor(syy, o, 64);  syz += __shfl_xor(syz, o, 64);
    szz += __shfl_xor(szz, o, 64);
  }

  // covariance (= centered^T centered) + closed-form symmetric 3x3 eigenvalues
  const float mx = sx * 0.0625f, my = sy * 0.0625f, mz = sz * 0.0625f;
  const float c00 = sxx - 16.f * mx * mx;
  const float c11 = syy - 16.f * my * my;
  const float c22 = szz - 16.f * mz * mz;
  const float c01 = sxy - 16.f * mx * my;
  const float c02 = sxz - 16.f * mx * mz;
  const float c12 = syz - 16.f * my * mz;

  const float tr = c00 + c11 + c22;
  const float q3 = tr * (1.f / 3.f);
  const float b0 = c00 - q3, b1 = c11 - q3, b2 = c22 - q3;
  const float p2 = b0 * b0 + b1 * b1 + b2 * b2 +
                   2.f * (c01 * c01 + c02 * c02 + c12 * c12);
  float e0, e1, e2;
  if (p2 < 1e-30f) {
    e0 = e1 = e2 = q3;
  } else {
    const float p  = sqrtf(p2 * (1.f / 6.f));
    const float ip = 1.f / p;
    const float m00 = b0 * ip, m11 = b1 * ip, m22 = b2 * ip;
    const float m01 = c01 * ip, m02 = c02 * ip, m12 = c12 * ip;
    const float det = m00 * (m11 * m22 - m12 * m12)
                    - m01 * (m01 * m22 - m12 * m02)
                    + m02 * (m01 * m12 - m11 * m02);
    float r = 0.5f * det;
    r = fminf(1.f, fmaxf(-1.f, r));
    const float phi = acosf(r) * (1.f / 3.f);
    e0 = q3 + 2.f * p * cosf(phi);
    e2 = q3 + 2.f * p * cosf(phi + 2.0943951023931953f);
    e1 = tr - e0 - e2;
  }

  if (lane == 0) {
    float* op = out + ((size_t)bb * NM + q) * 3;
    op[0] = e0; op[1] = e1; op[2] = e2;
  }
}

extern "C" void kernel_launch(void* const* d_in, const int* in_sizes, int n_in,
                              void* d_out, int out_size, void* d_ws, size_t ws_size,
                              hipStream_t stream) {
  const float* X  = (const float*)d_in[0];
  const float* uv = (const float*)d_in[1];
  float* out = (float*)d_out;
  char* ws = (char*)d_ws;
  float2* uvS = (float2*)(ws + WS_UVS);
  u16*    idxS = (u16*)(ws + WS_IDX);
  u32*    csP  = (u32*)(ws + WS_CS);

  bin_pts<<<dim3(NB), dim3(512), 0, stream>>>(uv, uvS, idxS, csP);
  knn_eig<<<dim3(NB * NM / WPB), dim3(BLK), 0, stream>>>(X, uv, uvS, idxS, csP, out);
}

// Round 4
// 50.153 us; speedup vs baseline: 1.6021x; 1.1347x over previous
//
#include <hip/hip_runtime.h>
#include <hip/hip_bf16.h>
#include <math.h>

typedef unsigned long long u64;
typedef unsigned int u32;
typedef unsigned short u16;

constexpr int NB  = 8;
constexpr int NM  = 4096;
constexpr int KNN = 16;
constexpr int WPB = 8;             // waves (= queries) per block
constexpr int BLK = WPB * 64;      // 512 threads
constexpr int GC  = 16;            // grid cells per dim
constexpr int NC  = GC * GC;       // 256 cells
constexpr int CSST = NC + 1;       // cellstart stride per batch
constexpr int SL1 = 5;             // slot cap, h=1 pass (320 candidates)
constexpr int SLG = 8;             // slot cap, generic pass (512 candidates)

// d_ws layout (fully rewritten every call -> poison-safe):
//   uvS  float2[NB][NM]   @ 0        (256 KB)  cell-ordered uv
//   idxS u16   [NB][NM]   @ 262144   ( 64 KB)  original point index
//   cs   u32   [NB][CSST] @ 327680   (  8 KB)  cell start offsets
constexpr size_t WS_UVS = 0;
constexpr size_t WS_IDX = 262144;
constexpr size_t WS_CS  = 327680;

__device__ __forceinline__ u64 shflx64(u64 v, int m) {
  unsigned lo = (unsigned)v, hi = (unsigned)(v >> 32);
  lo = __shfl_xor(lo, m, 64);
  hi = __shfl_xor(hi, m, 64);
  return ((u64)hi << 32) | lo;
}

__device__ __forceinline__ int wave_sum(int c) {
  #pragma unroll
  for (int o = 32; o > 0; o >>= 1) c += __shfl_xor(c, o, 64);
  return c;
}

__device__ __forceinline__ int rfl(int x) {           // force SGPR -> scalar branches
  return __builtin_amdgcn_readfirstlane(x);
}

// ---------------- binning: counting-sort each batch's uv into 16x16 cells ----
__global__ __launch_bounds__(512)
void bin_pts(const float* __restrict__ uv, float2* __restrict__ uvS,
             u16* __restrict__ idxS, u32* __restrict__ cs) {
  __shared__ u32 cnt[NC];
  __shared__ u32 offs[NC];
  __shared__ u32 wtot[4];
  const int bb  = blockIdx.x;
  const int tid = threadIdx.x;

  if (tid < NC) cnt[tid] = 0;
  __syncthreads();

  float2 c8[8];
  int cell[8];
  #pragma unroll
  for (int i = 0; i < 8; ++i) {
    const int p = tid + i * 512;
    const float2 c = ((const float2*)(uv + (size_t)bb * NM * 2))[p];
    int cx = (int)(c.x * (float)GC); cx = cx > GC - 1 ? GC - 1 : (cx < 0 ? 0 : cx);
    int cy = (int)(c.y * (float)GC); cy = cy > GC - 1 ? GC - 1 : (cy < 0 ? 0 : cy);
    c8[i] = c; cell[i] = cy * GC + cx;
    atomicAdd(&cnt[cell[i]], 1u);
  }
  __syncthreads();

  if (tid < NC) {
    const int lane = tid & 63;
    u32 inc = cnt[tid];
    #pragma unroll
    for (int o = 1; o < 64; o <<= 1) {
      const u32 t = __shfl_up(inc, o, 64);
      if (lane >= o) inc += t;
    }
    offs[tid] = inc;
    if (lane == 63) wtot[tid >> 6] = inc;
  }
  __syncthreads();
  if (tid < NC) {
    const int w = tid >> 6;
    u32 base = 0;
    #pragma unroll
    for (int i = 0; i < 3; ++i) base += (i < w) ? wtot[i] : 0;
    const u32 excl = base + offs[tid] - cnt[tid];
    cs[bb * CSST + tid] = excl;
    offs[tid] = excl;
    if (tid == 0) cs[bb * CSST + NC] = NM;
  }
  __syncthreads();

  #pragma unroll
  for (int i = 0; i < 8; ++i) {
    const int p = tid + i * 512;
    const u32 pos = atomicAdd(&offs[cell[i]], 1u);
    uvS[(size_t)bb * NM + pos]  = c8[i];
    idxS[(size_t)bb * NM + pos] = (u16)p;
  }
}

// ---------------- main: grid-pruned exact 16-NN + covariance eigenvalues ----
__global__ __launch_bounds__(BLK, 6)
void knn_eig(const float* __restrict__ X, const float* __restrict__ uv,
             const float2* __restrict__ uvS, const u16* __restrict__ idxS,
             const u32* __restrict__ cs, float* __restrict__ out) {
  __shared__ __align__(16) float2 uvL[NM];   // 32 KB cell-ordered uv
  __shared__ __align__(16) u16 idxL[NM];     //  8 KB original indices
  __shared__ u32 csL[CSST];                  //  1 KB cell starts
  __shared__ u64 surv[WPB][64];              //  4 KB survivor buffers

  const int tid  = threadIdx.x;
  const int lane = tid & 63;
  const int wv   = tid >> 6;
  const int bb   = blockIdx.x >> 9;                 // 512 blocks per batch
  const int q    = ((blockIdx.x & 511) << 3) + wv;

  {
    const float4* g = (const float4*)(uvS + (size_t)bb * NM);
    float4* s = (float4*)uvL;
    #pragma unroll
    for (int i = 0; i < 4; ++i) s[tid + i * BLK] = g[tid + i * BLK];
    ((float4*)idxL)[tid] = ((const float4*)(idxS + (size_t)bb * NM))[tid];
    if (tid < CSST) csL[tid] = cs[bb * CSST + tid];
  }
  __syncthreads();

  const float qu = uv[(size_t)bb * NM * 2 + 2 * q];
  const float qv = uv[(size_t)bb * NM * 2 + 2 * q + 1];
  int cx = (int)(qu * (float)GC); cx = cx > GC - 1 ? GC - 1 : (cx < 0 ? 0 : cx);
  int cy = (int)(qv * (float)GC); cy = cy > GC - 1 ? GC - 1 : (cy < 0 ? 0 : cy);

  float d[SLG];
  int   ca[SLG];
  #pragma unroll
  for (int t = 0; t < SLG; ++t) d[t] = 1e30f;

  int total = 0, ts = 0;

  // ---- h=1 pass (common case): 3-row specialized ring ----
  {
    const int x0 = cx > 0 ? cx - 1 : 0, x1 = cx < GC - 1 ? cx + 1 : GC - 1;
    const int y0 = cy > 0 ? cy - 1 : 0, y1 = cy < GC - 1 ? cy + 1 : GC - 1;
    int rs0, rs1, rs2, rc0, rc1;
    int cum;
    {
      const u32 s0 = csL[y0 * GC + x0], e0 = csL[y0 * GC + x1 + 1];
      rs0 = (int)s0; cum = (int)(e0 - s0); rc0 = cum;
      const u32 s1 = csL[(y0 + 1) * GC + x0], e1 = csL[(y0 + 1) * GC + x1 + 1];
      rs1 = (int)s1; cum += (int)(e1 - s1); rc1 = cum;
      const bool ok2 = (y0 + 2) <= y1;
      const u32 s2 = csL[ok2 ? ((y0 + 2) * GC + x0) : 0];
      const u32 e2 = csL[ok2 ? ((y0 + 2) * GC + x1 + 1) : 0];
      rs2 = (int)s2; cum += ok2 ? (int)(e2 - s2) : 0;
    }
    total = rfl(cum);
    ts = (total + 63) >> 6;
    #pragma unroll
    for (int t = 0; t < SL1; ++t) {
      if (t >= ts) break;                            // wave-uniform (scalar) break
      const int L = t * 64 + lane;
      int addr = rs0 + L;
      if (L >= rc0) addr = rs1 + (L - rc0);
      if (L >= rc1) addr = rs2 + (L - rc1);
      float dd = 1e30f;
      if (L < total) {
        const float2 c = uvL[addr];
        const float dx = __fsub_rn(qu, c.x);
        const float dy = __fsub_rn(qv, c.y);
        dd = __fadd_rn(__fmul_rn(dx, dx), __fmul_rn(dy, dy));
      }
      d[t] = dd; ca[t] = addr;
    }
  }

  // ---- threshold ladder: tau1 (tight, ~22 survivors) -> (1/16)^2 (covered) ----
  // exactness: any tau <= (h/16)^2 with >=16 survivors contains the true top-16.
  float hi2 = 0.0017f;
  int cl = 0;
  #pragma unroll
  for (int t = 0; t < SLG; ++t) { if (t >= ts) break; cl += (d[t] <= hi2); }
  int cnt = rfl(wave_sum(cl));
  if (cnt < KNN) {
    hi2 = 0.00390625f;                               // (1/16)^2 exactly
    cl = 0;
    #pragma unroll
    for (int t = 0; t < SLG; ++t) { if (t >= ts) break; cl += (d[t] <= hi2); }
    cnt = rfl(wave_sum(cl));
  }

  // ---- rare escalation h=2..5 (recompute distances on bigger ring) ----
  for (int h = 2; cnt < KNN && h <= 5; ++h) {
    const int x0 = cx - h < 0 ? 0 : cx - h, x1 = cx + h > GC - 1 ? GC - 1 : cx + h;
    const int y0 = cy - h < 0 ? 0 : cy - h, y1 = cy + h > GC - 1 ? GC - 1 : cy + h;
    int rstart[7], rcum[7];
    int cum = 0;
    #pragma unroll
    for (int r = 0; r < 7; ++r) {
      const int y = y0 + r;
      const bool ok = (y <= y1);
      const u32 s = csL[ok ? (y * GC + x0) : 0];
      const u32 e = csL[ok ? (y * GC + x1 + 1) : 0];
      rstart[r] = (int)s;
      cum += ok ? (int)(e - s) : 0;
      rcum[r] = cum;
    }
    total = rfl(cum);
    ts = (total + 63) >> 6;
    const float hv = (float)h * 0.0625f;
    hi2 = hv * hv;
    cl = 0;
    #pragma unroll
    for (int t = 0; t < SLG; ++t) {
      if (t >= ts) break;
      const int L = t * 64 + lane;
      int addr = rstart[0] + L;
      #pragma unroll
      for (int r = 1; r < 7; ++r)
        if (L >= rcum[r - 1]) addr = rstart[r] + (L - rcum[r - 1]);
      float dd = 1e30f;
      if (L < total) {
        const float2 c = uvL[addr];
        const float dx = __fsub_rn(qu, c.x);
        const float dy = __fsub_rn(qv, c.y);
        dd = __fadd_rn(__fmul_rn(dx, dx), __fmul_rn(dy, dy));
      }
      d[t] = dd; ca[t] = addr;
      cl += (dd <= hi2);
    }
    cnt = rfl(wave_sum(cl));
  }

  // ---- narrow threshold until survivors fit one-per-lane (rare) ----
  {
    float lo = 0.f;
    while (cnt > 64) {
      const float mid = 0.5f * (lo + hi2);
      if (!(mid > lo && mid < hi2)) break;
      int c = 0;
      #pragma unroll
      for (int t = 0; t < SLG; ++t) { if (t >= ts) break; c += (d[t] <= mid); }
      const int tt = rfl(wave_sum(c));
      if (tt >= KNN) { hi2 = mid; cnt = tt; cl = c; } else lo = mid;
    }
  }

  // ---- compact survivors, key = (dist_bits<<32) | orig_idx ----
  int inc = cl;
  #pragma unroll
  for (int o = 1; o < 64; o <<= 1) {
    const int t = __shfl_up(inc, o, 64);
    if (lane >= o) inc += t;
  }
  int pos = inc - cl;
  u64* sb = surv[wv];
  #pragma unroll
  for (int t = 0; t < SLG; ++t) {
    if (t >= ts) break;
    if (d[t] <= hi2) {
      if (pos < 64)
        sb[pos] = ((u64)__float_as_uint(d[t]) << 32) | (u64)idxL[ca[t]];
      ++pos;
    }
  }

  // ---- bitonic sort -> lanes 0..15 hold the exact top-16 ----
  const int S = cnt < 64 ? cnt : 64;
  u64 v = (lane < S) ? sb[lane] : ~0ull;
  if (cnt <= 32) {                                   // 15-stage 32-wide net (~75%)
    #pragma unroll
    for (int k = 2; k <= 32; k <<= 1) {
      #pragma unroll
      for (int j = k >> 1; j > 0; j >>= 1) {
        const u64 o = shflx64(v, j);
        const bool keepmin = ((lane & j) == 0) == ((lane & k) == 0);
        const u64 mn = (v < o) ? v : o;
        const u64 mx = (v < o) ? o : v;
        v = keepmin ? mn : mx;
      }
    }
  } else {                                           // full 21-stage 64-wide net
    #pragma unroll
    for (int k = 2; k <= 64; k <<= 1) {
      #pragma unroll
      for (int j = k >> 1; j > 0; j >>= 1) {
        const u64 o = shflx64(v, j);
        const bool keepmin = ((lane & j) == 0) == ((lane & k) == 0);
        const u64 mn = (v < o) ? v : o;
        const u64 mx = (v < o) ? o : v;
        v = keepmin ? mn : mx;
      }
    }
  }

  // ---- gather X, reduce 9 moment sums over lanes 0..15 ----
  float x = 0.f, y = 0.f, z = 0.f;
  if (lane < KNN) {
    const int idx = (int)(u32)v & 0xFFF;             // orig index (<4096), clamped
    const float* Xp = X + ((size_t)bb * NM + idx) * 3;
    x = Xp[0]; y = Xp[1]; z = Xp[2];
  }
  float sx = x, sy = y, sz = z;
  float sxx = x * x, sxy = x * y, sxz = x * z;
  float syy = y * y, syz = y * z, szz = z * z;
  #pragma unroll
  for (int o = 8; o > 0; o >>= 1) {
    sx  += __shfl_xor(sx,  o, 64);  sy  += __shfl_xor(sy,  o, 64);
    sz  += __shfl_xor(sz,  o, 64);  sxx += __shfl_xor(sxx, o, 64);
    sxy += __shfl_xor(sxy, o, 64);  sxz += __shfl_xor(sxz, o, 64);
    syy += __shfl_xor(syy, o, 64);  syz += __shfl_xor(syz, o, 64);
    szz += __shfl_xor(szz, o, 64);
  }

  // ---- covariance + closed-form symmetric 3x3 eigenvalues ----
  const float mx = sx * 0.0625f, my = sy * 0.0625f, mz = sz * 0.0625f;
  const float c00 = sxx - 16.f * mx * mx;
  const float c11 = syy - 16.f * my * my;
  const float c22 = szz - 16.f * mz * mz;
  const float c01 = sxy - 16.f * mx * my;
  const float c02 = sxz - 16.f * mx * mz;
  const float c12 = syz - 16.f * my * mz;

  const float tr = c00 + c11 + c22;
  const float q3 = tr * (1.f / 3.f);
  const float b0 = c00 - q3, b1 = c11 - q3, b2 = c22 - q3;
  const float p2 = b0 * b0 + b1 * b1 + b2 * b2 +
                   2.f * (c01 * c01 + c02 * c02 + c12 * c12);
  float e0, e1, e2;
  if (p2 < 1e-30f) {
    e0 = e1 = e2 = q3;
  } else {
    const float p  = sqrtf(p2 * (1.f / 6.f));
    const float ip = 1.f / p;
    const float m00 = b0 * ip, m11 = b1 * ip, m22 = b2 * ip;
    const float m01 = c01 * ip, m02 = c02 * ip, m12 = c12 * ip;
    const float det = m00 * (m11 * m22 - m12 * m12)
                    - m01 * (m01 * m22 - m12 * m02)
                    + m02 * (m01 * m12 - m11 * m02);
    float r = 0.5f * det;
    r = fminf(1.f, fmaxf(-1.f, r));
    const float phi = acosf(r) * (1.f / 3.f);
    float sphi, cphi;
    __sincosf(phi, &sphi, &cphi);
    e0 = q3 + 2.f * p * cphi;                                      // largest
    e2 = q3 + 2.f * p * (-0.5f * cphi - 0.8660254037844386f * sphi); // smallest
    e1 = tr - e0 - e2;
  }

  if (lane == 0) {
    float* op = out + ((size_t)bb * NM + q) * 3;
    op[0] = e0; op[1] = e1; op[2] = e2;
  }
}

extern "C" void kernel_launch(void* const* d_in, const int* in_sizes, int n_in,
                              void* d_out, int out_size, void* d_ws, size_t ws_size,
                              hipStream_t stream) {
  const float* X  = (const float*)d_in[0];
  const float* uv = (const float*)d_in[1];
  float* out = (float*)d_out;
  char* ws = (char*)d_ws;
  float2* uvS = (float2*)(ws + WS_UVS);
  u16*    idxS = (u16*)(ws + WS_IDX);
  u32*    csP  = (u32*)(ws + WS_CS);

  bin_pts<<<dim3(NB), dim3(512), 0, stream>>>(uv, uvS, idxS, csP);
  knn_eig<<<dim3(NB * NM / WPB), dim3(BLK), 0, stream>>>(X, uv, uvS, idxS, csP, out);
}

// Round 5
// 35.805 us; speedup vs baseline: 2.2440x; 1.4007x over previous
//
#include <hip/hip_runtime.h>
#include <hip/hip_bf16.h>
#include <math.h>

typedef unsigned long long u64;
typedef unsigned int u32;
typedef unsigned short u16;

constexpr int NB  = 8;
constexpr int NM  = 4096;
constexpr int KNN = 16;
constexpr int WPB = 8;             // waves (= queries) per block
constexpr int BLK = WPB * 64;      // 512 threads
constexpr int GC  = 16;            // grid cells per dim
constexpr int NC  = GC * GC;       // 256 cells
constexpr int CSST = NC + 1;       // cellstart stride per batch
constexpr int SL1 = 6;             // slot cap, h=1 pass (384 candidates)
constexpr int SLG = 8;             // slot cap, generic pass (512 candidates)

// d_ws layout (fully rewritten every call -> poison-safe):
//   uvS  float2[NB][NM]   @ 0        (256 KB)  cell-ordered uv
//   idxS u16   [NB][NM]   @ 262144   ( 64 KB)  original point index
//   cs   u32   [NB][CSST] @ 327680   (  8 KB)  cell start offsets
constexpr size_t WS_UVS = 0;
constexpr size_t WS_IDX = 262144;
constexpr size_t WS_CS  = 327680;

__device__ __forceinline__ u64 shflx64(u64 v, int m) {
  unsigned lo = (unsigned)v, hi = (unsigned)(v >> 32);
  lo = __shfl_xor(lo, m, 64);
  hi = __shfl_xor(hi, m, 64);
  return ((u64)hi << 32) | lo;
}

__device__ __forceinline__ int rfl(int x) {           // force SGPR -> scalar path
  return __builtin_amdgcn_readfirstlane(x);
}

__device__ __forceinline__ int lanes_below(u64 m) {   // popcount of mask below lane
  return (int)__builtin_amdgcn_mbcnt_hi((u32)(m >> 32),
             __builtin_amdgcn_mbcnt_lo((u32)m, 0u));
}

// ---------------- binning: counting-sort each batch's uv into 16x16 cells ----
__global__ __launch_bounds__(512)
void bin_pts(const float* __restrict__ uv, float2* __restrict__ uvS,
             u16* __restrict__ idxS, u32* __restrict__ cs) {
  __shared__ u32 cnt[NC];
  __shared__ u32 offs[NC];
  __shared__ u32 wtot[4];
  const int bb  = blockIdx.x;
  const int tid = threadIdx.x;

  if (tid < NC) cnt[tid] = 0;
  __syncthreads();

  float2 c8[8];
  int cell[8];
  #pragma unroll
  for (int i = 0; i < 8; ++i) {
    const int p = tid + i * 512;
    const float2 c = ((const float2*)(uv + (size_t)bb * NM * 2))[p];
    int cx = (int)(c.x * (float)GC); cx = cx > GC - 1 ? GC - 1 : (cx < 0 ? 0 : cx);
    int cy = (int)(c.y * (float)GC); cy = cy > GC - 1 ? GC - 1 : (cy < 0 ? 0 : cy);
    c8[i] = c; cell[i] = cy * GC + cx;
    atomicAdd(&cnt[cell[i]], 1u);
  }
  __syncthreads();

  if (tid < NC) {
    const int lane = tid & 63;
    u32 inc = cnt[tid];
    #pragma unroll
    for (int o = 1; o < 64; o <<= 1) {
      const u32 t = __shfl_up(inc, o, 64);
      if (lane >= o) inc += t;
    }
    offs[tid] = inc;
    if (lane == 63) wtot[tid >> 6] = inc;
  }
  __syncthreads();
  if (tid < NC) {
    const int w = tid >> 6;
    u32 base = 0;
    #pragma unroll
    for (int i = 0; i < 3; ++i) base += (i < w) ? wtot[i] : 0;
    const u32 excl = base + offs[tid] - cnt[tid];
    cs[bb * CSST + tid] = excl;
    offs[tid] = excl;
    if (tid == 0) cs[bb * CSST + NC] = NM;
  }
  __syncthreads();

  #pragma unroll
  for (int i = 0; i < 8; ++i) {
    const int p = tid + i * 512;
    const u32 pos = atomicAdd(&offs[cell[i]], 1u);
    uvS[(size_t)bb * NM + pos]  = c8[i];
    idxS[(size_t)bb * NM + pos] = (u16)p;
  }
}

// ---------------- main: grid-pruned exact 16-NN + covariance eigenvalues ----
// No per-block staging: uvS/idxS are L2-resident (32KB+8KB per batch shared by
// 512 blocks); cell starts via wave-uniform scalar loads. LDS = surv only.
__global__ __launch_bounds__(BLK, 8)
void knn_eig(const float* __restrict__ X, const float* __restrict__ uv,
             const float2* __restrict__ uvS, const u16* __restrict__ idxS,
             const u32* __restrict__ cs, float* __restrict__ out) {
  __shared__ u64 surv[WPB][64];              // 4 KB survivor buffers

  const int tid  = threadIdx.x;
  const int lane = tid & 63;
  const int wv   = tid >> 6;
  const int bb   = blockIdx.x >> 9;                 // 512 blocks per batch
  const int q    = rfl(((blockIdx.x & 511) << 3) + wv);

  const float qu = uv[((size_t)bb * NM + q) * 2];
  const float qv = uv[((size_t)bb * NM + q) * 2 + 1];
  int cxv = (int)(qu * (float)GC); cxv = cxv > GC - 1 ? GC - 1 : (cxv < 0 ? 0 : cxv);
  int cyv = (int)(qv * (float)GC); cyv = cyv > GC - 1 ? GC - 1 : (cyv < 0 ? 0 : cyv);
  const int cx = rfl(cxv), cy = rfl(cyv);
  const u32* csb = cs + bb * CSST;
  const float2* uvb = uvS + (size_t)bb * NM;
  const u16* idxb = idxS + (size_t)bb * NM;

  float d[SLG];
  int   ca[SLG];
  #pragma unroll
  for (int t = 0; t < SLG; ++t) d[t] = 1e30f;

  int total = 0, ts = 0;

  // ---- h=1 pass (common case): 3-row ring, scalar cellstart loads ----
  {
    const int x0 = cx > 0 ? cx - 1 : 0, x1 = cx < GC - 1 ? cx + 1 : GC - 1;
    const int y0 = cy > 0 ? cy - 1 : 0, y1 = cy < GC - 1 ? cy + 1 : GC - 1;
    const int rs0 = (int)csb[y0 * GC + x0];
    const int rc0 = (int)csb[y0 * GC + x1 + 1] - rs0;
    const int rs1 = (int)csb[(y0 + 1) * GC + x0];
    const int rc1 = rc0 + (int)csb[(y0 + 1) * GC + x1 + 1] - rs1;
    const bool ok2 = (y0 + 2) <= y1;
    const int rs2 = (int)csb[ok2 ? ((y0 + 2) * GC + x0) : 0];
    const int e2  = (int)csb[ok2 ? ((y0 + 2) * GC + x1 + 1) : 0];
    total = rc1 + (ok2 ? (e2 - rs2) : 0);
    ts = (total + 63) >> 6;
    #pragma unroll
    for (int t = 0; t < SL1; ++t) {
      if (t >= ts) break;                            // wave-uniform scalar break
      const int L = t * 64 + lane;
      int addr = rs0 + L;
      if (L >= rc0) addr = rs1 + (L - rc0);
      if (L >= rc1) addr = rs2 + (L - rc1);
      float dd = 1e30f;
      if (L < total) {
        const float2 c = uvb[addr];
        const float dx = __fsub_rn(qu, c.x);
        const float dy = __fsub_rn(qv, c.y);
        dd = __fadd_rn(__fmul_rn(dx, dx), __fmul_rn(dy, dy));
      }
      d[t] = dd; ca[t] = addr;
    }
  }

  // ---- threshold ladder via ballot counts (SALU, no shuffle chains) ----
  // exactness: any tau <= (h/16)^2 with >=16 survivors contains the true top-16.
  float hi2 = 0.0017f;
  int cnt = 0;
  #pragma unroll
  for (int t = 0; t < SLG; ++t) { if (t >= ts) break; cnt += (int)__popcll(__ballot(d[t] <= hi2)); }
  if (cnt < KNN) {
    hi2 = 0.00390625f;                               // (1/16)^2 exactly
    cnt = 0;
    #pragma unroll
    for (int t = 0; t < SLG; ++t) { if (t >= ts) break; cnt += (int)__popcll(__ballot(d[t] <= hi2)); }
  }

  // ---- rare escalation h=2..5 ----
  for (int h = 2; cnt < KNN && h <= 5; ++h) {
    const int x0 = cx - h < 0 ? 0 : cx - h, x1 = cx + h > GC - 1 ? GC - 1 : cx + h;
    const int y0 = cy - h < 0 ? 0 : cy - h, y1 = cy + h > GC - 1 ? GC - 1 : cy + h;
    int rstart[7], rcum[7];
    int cum = 0;
    #pragma unroll
    for (int r = 0; r < 7; ++r) {
      const int y = y0 + r;
      const bool ok = (y <= y1);
      const u32 s = csb[ok ? (y * GC + x0) : 0];
      const u32 e = csb[ok ? (y * GC + x1 + 1) : 0];
      rstart[r] = (int)s;
      cum += ok ? (int)(e - s) : 0;
      rcum[r] = cum;
    }
    total = cum;
    ts = (total + 63) >> 6;
    const float hv = (float)h * 0.0625f;
    hi2 = hv * hv;
    cnt = 0;
    #pragma unroll
    for (int t = 0; t < SLG; ++t) {
      if (t >= ts) break;
      const int L = t * 64 + lane;
      int addr = rstart[0] + L;
      #pragma unroll
      for (int r = 1; r < 7; ++r)
        if (L >= rcum[r - 1]) addr = rstart[r] + (L - rcum[r - 1]);
      float dd = 1e30f;
      if (L < total) {
        const float2 c = uvb[addr];
        const float dx = __fsub_rn(qu, c.x);
        const float dy = __fsub_rn(qv, c.y);
        dd = __fadd_rn(__fmul_rn(dx, dx), __fmul_rn(dy, dy));
      }
      d[t] = dd; ca[t] = addr;
      cnt += (int)__popcll(__ballot(dd <= hi2));
    }
  }

  // ---- narrow threshold until survivors fit one-per-lane (rare) ----
  {
    float lo = 0.f;
    while (cnt > 64) {
      const float mid = 0.5f * (lo + hi2);
      if (!(mid > lo && mid < hi2)) break;
      int c = 0;
      #pragma unroll
      for (int t = 0; t < SLG; ++t) { if (t >= ts) break; c += (int)__popcll(__ballot(d[t] <= mid)); }
      if (c >= KNN) { hi2 = mid; cnt = c; } else lo = mid;
    }
  }

  // ---- compact survivors via ballot/mbcnt, key = (dist_bits<<32)|orig_idx ----
  u64* sb = surv[wv];
  {
    int base = 0;
    #pragma unroll
    for (int t = 0; t < SLG; ++t) {
      if (t >= ts) break;
      const u64 m = __ballot(d[t] <= hi2);
      if (d[t] <= hi2) {
        const int pos = base + lanes_below(m);
        if (pos < 64) {
          const u32 oid = idxb[ca[t]];               // L2-resident u16 gather
          sb[pos] = ((u64)__float_as_uint(d[t]) << 32) | oid;
        }
      }
      base += (int)__popcll(m);
    }
  }

  // ---- bitonic top-16 selection (not a full sort) ----
  const int S = cnt < 64 ? cnt : 64;
  u64 v = (lane < S) ? sb[lane] : ~0ull;
  const int csel = rfl(cnt);
  if (csel > KNN) {
    // phase 1: sort 16-lane runs, direction alternates by bit4 (10 stages)
    const int dir4 = (lane >> 4) & 1;
    #pragma unroll
    for (int k = 2; k <= 16; k <<= 1) {
      #pragma unroll
      for (int j = k >> 1; j > 0; j >>= 1) {
        const u64 o = shflx64(v, j);
        const bool up = (((lane & k & 15) == 0) != (dir4 != 0));  // ascending?
        const bool km = (((lane & j) == 0) == up);                // keep min here?
        v = ((v < o) == km) ? v : o;
      }
    }
    // phase 2: xor-16 min-prune -> lanes with bit4==0 hold top16 of each 32
    {
      const u64 o = shflx64(v, 16);
      const bool km = ((lane & 16) == 0);
      v = ((v < o) == km) ? v : o;
    }
    if (csel > 32) {
      // phase 3: re-sort the two bitonic-16 runs (g0 asc, g2 desc), 4 stages
      const int dir5 = (lane >> 5) & 1;
      #pragma unroll
      for (int j = 8; j > 0; j >>= 1) {
        const u64 o = shflx64(v, j);
        const bool km = (((lane & j) == 0) != (dir5 != 0));
        v = ((v < o) == km) ? v : o;
      }
      // phase 4: xor-32 min-prune -> lanes 0..15 hold top16 of 64
      const u64 o = shflx64(v, 32);
      const bool km = ((lane & 32) == 0);
      v = ((v < o) == km) ? v : o;
    }
  }
  // csel == 16: survivors (lanes 0..15) are exactly the winners, no sort.

  // ---- gather X, reduce 9 moment sums over lanes 0..15 ----
  float x = 0.f, y = 0.f, z = 0.f;
  if (lane < KNN) {
    const int idx = (int)(u32)v & 0xFFF;             // orig index (<4096)
    const float* Xp = X + ((size_t)bb * NM + idx) * 3;
    x = Xp[0]; y = Xp[1]; z = Xp[2];
  }
  float sx = x, sy = y, sz = z;
  float sxx = x * x, sxy = x * y, sxz = x * z;
  float syy = y * y, syz = y * z, szz = z * z;
  #pragma unroll
  for (int o = 8; o > 0; o >>= 1) {
    sx  += __shfl_xor(sx,  o, 64);  sy  += __shfl_xor(sy,  o, 64);
    sz  += __shfl_xor(sz,  o, 64);  sxx += __shfl_xor(sxx, o, 64);
    sxy += __shfl_xor(sxy, o, 64);  sxz += __shfl_xor(sxz, o, 64);
    syy += __shfl_xor(syy, o, 64);  syz += __shfl_xor(syz, o, 64);
    szz += __shfl_xor(szz, o, 64);
  }

  // ---- covariance + closed-form symmetric 3x3 eigenvalues ----
  const float mx = sx * 0.0625f, my = sy * 0.0625f, mz = sz * 0.0625f;
  const float c00 = sxx - 16.f * mx * mx;
  const float c11 = syy - 16.f * my * my;
  const float c22 = szz - 16.f * mz * mz;
  const float c01 = sxy - 16.f * mx * my;
  const float c02 = sxz - 16.f * mx * mz;
  const float c12 = syz - 16.f * my * mz;

  const float tr = c00 + c11 + c22;
  const float q3 = tr * (1.f / 3.f);
  const float b0 = c00 - q3, b1 = c11 - q3, b2 = c22 - q3;
  const float p2 = b0 * b0 + b1 * b1 + b2 * b2 +
                   2.f * (c01 * c01 + c02 * c02 + c12 * c12);
  float e0, e1, e2;
  if (p2 < 1e-30f) {
    e0 = e1 = e2 = q3;
  } else {
    const float p  = sqrtf(p2 * (1.f / 6.f));
    const float ip = 1.f / p;
    const float m00 = b0 * ip, m11 = b1 * ip, m22 = b2 * ip;
    const float m01 = c01 * ip, m02 = c02 * ip, m12 = c12 * ip;
    const float det = m00 * (m11 * m22 - m12 * m12)
                    - m01 * (m01 * m22 - m12 * m02)
                    + m02 * (m01 * m12 - m11 * m02);
    float r = 0.5f * det;
    r = fminf(1.f, fmaxf(-1.f, r));
    const float phi = acosf(r) * (1.f / 3.f);
    float sphi, cphi;
    __sincosf(phi, &sphi, &cphi);
    e0 = q3 + 2.f * p * cphi;                                        // largest
    e2 = q3 + 2.f * p * (-0.5f * cphi - 0.8660254037844386f * sphi); // smallest
    e1 = tr - e0 - e2;
  }

  if (lane == 0) {
    float* op = out + ((size_t)bb * NM + q) * 3;
    op[0] = e0; op[1] = e1; op[2] = e2;
  }
}

extern "C" void kernel_launch(void* const* d_in, const int* in_sizes, int n_in,
                              void* d_out, int out_size, void* d_ws, size_t ws_size,
                              hipStream_t stream) {
  const float* X  = (const float*)d_in[0];
  const float* uv = (const float*)d_in[1];
  float* out = (float*)d_out;
  char* ws = (char*)d_ws;
  float2* uvS = (float2*)(ws + WS_UVS);
  u16*    idxS = (u16*)(ws + WS_IDX);
  u32*    csP  = (u32*)(ws + WS_CS);

  bin_pts<<<dim3(NB), dim3(512), 0, stream>>>(uv, uvS, idxS, csP);
  knn_eig<<<dim3(NB * NM / WPB), dim3(BLK), 0, stream>>>(X, uv, uvS, idxS, csP, out);
}

// Round 6
// 30.105 us; speedup vs baseline: 2.6689x; 1.1893x over previous
//
#include <hip/hip_runtime.h>
#include <hip/hip_bf16.h>
#include <math.h>

typedef unsigned long long u64;
typedef unsigned int u32;
typedef unsigned short u16;

constexpr int NB  = 8;
constexpr int NM  = 4096;
constexpr int KNN = 16;
constexpr int WPB = 8;             // waves per block; 2 queries per wave
constexpr int QPB = WPB * 2;       // 16 queries per block
constexpr int BLK = WPB * 64;      // 512 threads
constexpr int GC  = 16;            // grid cells per dim
constexpr int NC  = GC * GC;       // 256 cells
constexpr int CSST = NC + 1;       // cellstart stride per batch
constexpr int SLG = 8;             // candidate slots per lane

// d_ws layout (fully rewritten every call -> poison-safe):
//   uvS  float2[NB][NM]   @ 0        (256 KB)  cell-ordered uv
//   idxS u16   [NB][NM]   @ 262144   ( 64 KB)  original point index
//   cs   u32   [NB][CSST] @ 327680   (  8 KB)  cell start offsets
constexpr size_t WS_UVS = 0;
constexpr size_t WS_IDX = 262144;
constexpr size_t WS_CS  = 327680;

__device__ __forceinline__ u64 shflx64(u64 v, int m) {
  unsigned lo = (unsigned)v, hi = (unsigned)(v >> 32);
  lo = __shfl_xor(lo, m, 64);
  hi = __shfl_xor(hi, m, 64);
  return ((u64)hi << 32) | lo;
}

__device__ __forceinline__ int rfl(int x) {
  return __builtin_amdgcn_readfirstlane(x);
}

__device__ __forceinline__ int lanes_below(u64 m) {
  return (int)__builtin_amdgcn_mbcnt_hi((u32)(m >> 32),
             __builtin_amdgcn_mbcnt_lo((u32)m, 0u));
}

__device__ __forceinline__ u32 gmask(u64 m, int lane) {   // own 32-group's ballot bits
  return (lane & 32) ? (u32)(m >> 32) : (u32)m;
}

// ---------------- binning: counting-sort each batch's uv into 16x16 cells ----
__global__ __launch_bounds__(1024)
void bin_pts(const float* __restrict__ uv, float2* __restrict__ uvS,
             u16* __restrict__ idxS, u32* __restrict__ cs) {
  __shared__ u32 cnt[NC];
  __shared__ u32 offs[NC];
  __shared__ u32 wtot[4];
  const int bb  = blockIdx.x;
  const int tid = threadIdx.x;

  if (tid < NC) cnt[tid] = 0;
  __syncthreads();

  float2 c4[4];
  int cell[4];
  #pragma unroll
  for (int i = 0; i < 4; ++i) {
    const int p = tid + i * 1024;
    const float2 c = ((const float2*)(uv + (size_t)bb * NM * 2))[p];
    int cx = (int)(c.x * (float)GC); cx = cx > GC - 1 ? GC - 1 : (cx < 0 ? 0 : cx);
    int cy = (int)(c.y * (float)GC); cy = cy > GC - 1 ? GC - 1 : (cy < 0 ? 0 : cy);
    c4[i] = c; cell[i] = cy * GC + cx;
    atomicAdd(&cnt[cell[i]], 1u);
  }
  __syncthreads();

  if (tid < NC) {
    const int lane = tid & 63;
    u32 inc = cnt[tid];
    #pragma unroll
    for (int o = 1; o < 64; o <<= 1) {
      const u32 t = __shfl_up(inc, o, 64);
      if (lane >= o) inc += t;
    }
    offs[tid] = inc;
    if (lane == 63) wtot[tid >> 6] = inc;
  }
  __syncthreads();
  if (tid < NC) {
    const int w = tid >> 6;
    u32 base = 0;
    #pragma unroll
    for (int i = 0; i < 3; ++i) base += (i < w) ? wtot[i] : 0;
    const u32 excl = base + offs[tid] - cnt[tid];
    cs[bb * CSST + tid] = excl;
    offs[tid] = excl;
    if (tid == 0) cs[bb * CSST + NC] = NM;
  }
  __syncthreads();

  #pragma unroll
  for (int i = 0; i < 4; ++i) {
    const int p = tid + i * 1024;
    const u32 pos = atomicAdd(&offs[cell[i]], 1u);
    uvS[(size_t)bb * NM + pos]  = c4[i];
    idxS[(size_t)bb * NM + pos] = (u16)p;
  }
}

// ---------------- main: 2 queries/wave, grid-pruned exact 16-NN + eigen ----
__global__ __launch_bounds__(BLK, 8)
void knn_eig(const float* __restrict__ X, const float* __restrict__ uv,
             const float2* __restrict__ uvS, const u16* __restrict__ idxS,
             const u32* __restrict__ cs, float* __restrict__ out) {
  __shared__ u64 surv[WPB][64];              // 4 KB: 32 slots per query

  const int tid  = threadIdx.x;
  const int lane = tid & 63;
  const int sub  = lane & 31;                // lane within 32-group
  const int half = lane >> 5;                // which query of the pair
  const int wv   = tid >> 6;
  const int bb   = blockIdx.x >> 8;          // 256 blocks per batch
  const int q    = ((blockIdx.x & 255) << 4) + (wv << 1) + half;

  const float qu = uv[((size_t)bb * NM + q) * 2];
  const float qv = uv[((size_t)bb * NM + q) * 2 + 1];
  int cxv = (int)(qu * (float)GC); cxv = cxv > GC - 1 ? GC - 1 : (cxv < 0 ? 0 : cxv);
  int cyv = (int)(qv * (float)GC); cyv = cyv > GC - 1 ? GC - 1 : (cyv < 0 ? 0 : cyv);
  const u32* csb = cs + bb * CSST;
  const float2* uvb = uvS + (size_t)bb * NM;
  const u16* idxb = idxS + (size_t)bb * NM;

  float d[SLG];
  int   ca[SLG];
  #pragma unroll
  for (int t = 0; t < SLG; ++t) d[t] = 1e30f;

  constexpr float TAU1 = 0.0017f;            // ~22 expected survivors
  constexpr float TAU2 = 0.00390625f;        // (1/16)^2 exactly (covered radius)

  int total, tsw;
  // ---- h=1 ring (3 rows), per-group addressing, fused tau1 count ----
  int cnt = 0;
  {
    const int x0 = cxv > 0 ? cxv - 1 : 0, x1 = cxv < GC - 1 ? cxv + 1 : GC - 1;
    const int y0 = cyv > 0 ? cyv - 1 : 0, y1 = cyv < GC - 1 ? cyv + 1 : GC - 1;
    const int rs0 = (int)csb[y0 * GC + x0];
    const int rc0 = (int)csb[y0 * GC + x1 + 1] - rs0;
    const int rs1 = (int)csb[(y0 + 1) * GC + x0];
    const int rc1 = rc0 + (int)csb[(y0 + 1) * GC + x1 + 1] - rs1;
    const bool ok2 = (y0 + 2) <= y1;
    const int rs2 = (int)csb[ok2 ? ((y0 + 2) * GC + x0) : 0];
    const int re2 = (int)csb[ok2 ? ((y0 + 2) * GC + x1 + 1) : 0];
    total = rc1 + (ok2 ? (re2 - rs2) : 0);
    int ts = (total + 31) >> 5;
    tsw = rfl(max(ts, __shfl_xor(ts, 32, 64)));
    #pragma unroll
    for (int t = 0; t < SLG; ++t) {
      if (t >= tsw) break;                   // wave-uniform scalar break
      const int L = t * 32 + sub;
      int addr = rs0 + L;
      if (L >= rc0) addr = rs1 + (L - rc0);
      if (L >= rc1) addr = rs2 + (L - rc1);
      float dd = 1e30f;
      if (L < total) {
        const float2 c = uvb[addr];
        const float dx = __fsub_rn(qu, c.x);
        const float dy = __fsub_rn(qv, c.y);
        dd = __fadd_rn(__fmul_rn(dx, dx), __fmul_rn(dy, dy));
      }
      d[t] = dd; ca[t] = addr;
      cnt += (int)__popc(gmask(__ballot(dd <= TAU1), lane));
    }
  }

  // ---- tau ladder: group-wise escalate tau1 -> tau2 ----
  float hi2 = (cnt < KNN) ? TAU2 : TAU1;
  if (__any(cnt < KNN)) {
    int c2 = 0;
    #pragma unroll
    for (int t = 0; t < SLG; ++t) {
      if (t >= tsw) break;
      c2 += (int)__popc(gmask(__ballot(d[t] <= TAU2), lane));
    }
    if (cnt < KNN) cnt = c2;
  }

  // ---- group-wise narrow to <=32 survivors (tau2 path, ~8% of queries) ----
  {
    float lo = 0.f;
    for (int it = 0; __any(cnt > 32) && it < 40; ++it) {
      const float mid = 0.5f * (lo + hi2);
      int c = 0;
      #pragma unroll
      for (int t = 0; t < SLG; ++t) {
        if (t >= tsw) break;
        c += (int)__popc(gmask(__ballot(cnt > 32 && d[t] <= mid), lane));
      }
      if (cnt > 32) {
        if (!(mid > lo && mid < hi2)) { cnt = 32; }
        else if (c >= KNN) { hi2 = mid; cnt = c; }
        else lo = mid;
      }
    }
  }

  // ---- compact survivors into own 32-slot half of surv ----
  u64* sb = surv[wv];
  {
    int base = 0;
    #pragma unroll
    for (int t = 0; t < SLG; ++t) {
      if (t >= tsw) break;
      const bool p = d[t] <= hi2;
      const u32 mg = gmask(__ballot(p), lane);
      if (p) {
        const int pos = base + (int)__popc(mg & ((1u << sub) - 1u));
        if (pos < 32)
          sb[(half << 5) + pos] = ((u64)__float_as_uint(d[t]) << 32) | (u64)idxb[ca[t]];
      }
      base += (int)__popc(mg);
    }
  }

  // ---- cold escalation: serialize needy query onto the full wave ----
  if (__any(cnt < KNN)) {
    for (int g = 0; g < 2; ++g) {
      const int need = rfl((__shfl(cnt, g * 32, 64) < KNN) ? 1 : 0);
      if (!need) continue;
      const float gu = __shfl(qu, g * 32, 64);
      const float gv = __shfl(qv, g * 32, 64);
      const int gcx = rfl(__shfl(cxv, g * 32, 64));
      const int gcy = rfl(__shfl(cyv, g * 32, 64));
      float ghi = 0.f;
      int gcnt = 0, gts = 0, gtotal = 0;
      for (int h = 2; h <= 5; ++h) {
        const int x0 = gcx - h < 0 ? 0 : gcx - h, x1 = gcx + h > GC - 1 ? GC - 1 : gcx + h;
        const int y0 = gcy - h < 0 ? 0 : gcy - h, y1 = gcy + h > GC - 1 ? GC - 1 : gcy + h;
        int rstart[7], rcum[7];
        int cum = 0;
        #pragma unroll
        for (int r = 0; r < 7; ++r) {
          const int y = y0 + r;
          const bool ok = (y <= y1);
          const u32 s = csb[ok ? (y * GC + x0) : 0];
          const u32 e = csb[ok ? (y * GC + x1 + 1) : 0];
          rstart[r] = (int)s;
          cum += ok ? (int)(e - s) : 0;
          rcum[r] = cum;
        }
        gtotal = cum;
        gts = (gtotal + 63) >> 6; if (gts > SLG) gts = SLG;
        const float hv = (float)h * 0.0625f;
        ghi = hv * hv;
        gcnt = 0;
        for (int t = 0; t < gts; ++t) {
          const int L = t * 64 + lane;
          int addr = rstart[0] + L;
          #pragma unroll
          for (int r = 1; r < 7; ++r)
            if (L >= rcum[r - 1]) addr = rstart[r] + (L - rcum[r - 1]);
          float dd = 1e30f;
          if (L < gtotal) {
            const float2 c = uvb[addr];
            const float dx = __fsub_rn(gu, c.x);
            const float dy = __fsub_rn(gv, c.y);
            dd = __fadd_rn(__fmul_rn(dx, dx), __fmul_rn(dy, dy));
          }
          d[t] = dd; ca[t] = addr;
          gcnt += (int)__popcll(__ballot(dd <= ghi));
        }
        if (rfl(gcnt) >= KNN) break;
      }
      {
        float lo = 0.f;
        for (int it = 0; rfl(gcnt) > 32 && it < 40; ++it) {
          const float mid = 0.5f * (lo + ghi);
          if (!(mid > lo && mid < ghi)) break;
          int c = 0;
          for (int t = 0; t < gts; ++t) c += (int)__popcll(__ballot(d[t] <= mid));
          if (c >= KNN) { ghi = mid; gcnt = c; } else lo = mid;
        }
      }
      int base = 0;
      for (int t = 0; t < gts; ++t) {
        const bool p = d[t] <= ghi;
        const u64 m = __ballot(p);
        if (p) {
          const int pos = base + lanes_below(m);
          if (pos < 32)
            sb[(g << 5) + pos] = ((u64)__float_as_uint(d[t]) << 32) | (u64)idxb[ca[t]];
        }
        base += (int)__popcll(m);
      }
      if (half == g) cnt = gcnt < 32 ? gcnt : 32;
    }
  }

  // ---- per-group bitonic top-16 selection over 32 lanes ----
  const int S = cnt < 32 ? cnt : 32;
  u64 v = (sub < S) ? sb[lane] : ~0ull;
  if (cnt > KNN) {
    // phase 1: sort 16-lane runs, direction alternates on bit4 (10 stages)
    const int dir4 = (lane >> 4) & 1;
    #pragma unroll
    for (int k = 2; k <= 16; k <<= 1) {
      #pragma unroll
      for (int j = k >> 1; j > 0; j >>= 1) {
        const u64 o = shflx64(v, j);
        const bool up = (((lane & k & 15) == 0) != (dir4 != 0));
        const bool km = (((lane & j) == 0) == up);
        v = ((v < o) == km) ? v : o;
      }
    }
    // phase 2: xor-16 min-prune -> lanes with bit4==0 hold the top-16 set
    const u64 o = shflx64(v, 16);
    const bool km = ((lane & 16) == 0);
    v = ((v < o) == km) ? v : o;
  }

  // ---- gather X, reduce 9 moment sums within each 16-lane quarter ----
  float x = 0.f, y = 0.f, z = 0.f;
  if ((lane & 16) == 0) {
    const int idx = (int)(u32)v & 0xFFF;
    const float* Xp = X + ((size_t)bb * NM + idx) * 3;
    x = Xp[0]; y = Xp[1]; z = Xp[2];
  }
  float sx = x, sy = y, sz = z;
  float sxx = x * x, sxy = x * y, sxz = x * z;
  float syy = y * y, syz = y * z, szz = z * z;
  #pragma unroll
  for (int o = 8; o > 0; o >>= 1) {
    sx  += __shfl_xor(sx,  o, 64);  sy  += __shfl_xor(sy,  o, 64);
    sz  += __shfl_xor(sz,  o, 64);  sxx += __shfl_xor(sxx, o, 64);
    sxy += __shfl_xor(sxy, o, 64);  sxz += __shfl_xor(sxz, o, 64);
    syy += __shfl_xor(syy, o, 64);  syz += __shfl_xor(syz, o, 64);
    szz += __shfl_xor(szz, o, 64);
  }

  // ---- covariance + closed-form symmetric 3x3 eigenvalues ----
  const float mx = sx * 0.0625f, my = sy * 0.0625f, mz = sz * 0.0625f;
  const float c00 = sxx - 16.f * mx * mx;
  const float c11 = syy - 16.f * my * my;
  const float c22 = szz - 16.f * mz * mz;
  const float c01 = sxy - 16.f * mx * my;
  const float c02 = sxz - 16.f * mx * mz;
  const float c12 = syz - 16.f * my * mz;

  const float tr = c00 + c11 + c22;
  const float q3 = tr * (1.f / 3.f);
  const float b0 = c00 - q3, b1 = c11 - q3, b2 = c22 - q3;
  const float p2 = b0 * b0 + b1 * b1 + b2 * b2 +
                   2.f * (c01 * c01 + c02 * c02 + c12 * c12);
  float e0, e1, e2;
  if (p2 < 1e-30f) {
    e0 = e1 = e2 = q3;
  } else {
    const float p  = sqrtf(p2 * (1.f / 6.f));
    const float ip = 1.f / p;
    const float m00 = b0 * ip, m11 = b1 * ip, m22 = b2 * ip;
    const float m01 = c01 * ip, m02 = c02 * ip, m12 = c12 * ip;
    const float det = m00 * (m11 * m22 - m12 * m12)
                    - m01 * (m01 * m22 - m12 * m02)
                    + m02 * (m01 * m12 - m11 * m02);
    float r = 0.5f * det;
    r = fminf(1.f, fmaxf(-1.f, r));
    const float phi = acosf(r) * (1.f / 3.f);
    float sphi, cphi;
    __sincosf(phi, &sphi, &cphi);
    e0 = q3 + 2.f * p * cphi;                                        // largest
    e2 = q3 + 2.f * p * (-0.5f * cphi - 0.8660254037844386f * sphi); // smallest
    e1 = tr - e0 - e2;
  }

  if (sub == 0) {
    float* op = out + ((size_t)bb * NM + q) * 3;
    op[0] = e0; op[1] = e1; op[2] = e2;
  }
}

extern "C" void kernel_launch(void* const* d_in, const int* in_sizes, int n_in,
                              void* d_out, int out_size, void* d_ws, size_t ws_size,
                              hipStream_t stream) {
  const float* X  = (const float*)d_in[0];
  const float* uv = (const float*)d_in[1];
  float* out = (float*)d_out;
  char* ws = (char*)d_ws;
  float2* uvS = (float2*)(ws + WS_UVS);
  u16*    idxS = (u16*)(ws + WS_IDX);
  u32*    csP  = (u32*)(ws + WS_CS);

  bin_pts<<<dim3(NB), dim3(1024), 0, stream>>>(uv, uvS, idxS, csP);
  knn_eig<<<dim3(NB * NM / QPB), dim3(BLK), 0, stream>>>(X, uv, uvS, idxS, csP, out);
}

// Round 7
// 27.506 us; speedup vs baseline: 2.9211x; 1.0945x over previous
//
#include <hip/hip_runtime.h>
#include <hip/hip_bf16.h>
#include <math.h>

typedef unsigned long long u64;
typedef unsigned int u32;
typedef unsigned short u16;

constexpr int NB  = 8;
constexpr int NM  = 4096;
constexpr int KNN = 16;
constexpr int WPB = 8;             // waves per block; 4 queries per wave
constexpr int QPW = 4;
constexpr int QPB = WPB * QPW;     // 32 queries per block
constexpr int BLK = WPB * 64;      // 512 threads
constexpr int GC  = 16;
constexpr int NC  = GC * GC;
constexpr int CSST = NC + 1;
constexpr int SLG = 12;            // warm slots/lane (16 lanes): 192 cand capacity
constexpr int SLC = 8;             // cold slots/lane (64 lanes): 512 cand capacity

// d_ws layout (fully rewritten every call -> poison-safe):
constexpr size_t WS_UVS = 0;        // float2[NB][NM]   (256 KB) cell-ordered uv
constexpr size_t WS_IDX = 262144;   // u16   [NB][NM]   ( 64 KB) original index
constexpr size_t WS_CS  = 327680;   // u32   [NB][CSST] (  8 KB) cell starts

__device__ __forceinline__ u64 shflx64(u64 v, int m) {
  unsigned lo = (unsigned)v, hi = (unsigned)(v >> 32);
  lo = __shfl_xor(lo, m, 64);
  hi = __shfl_xor(hi, m, 64);
  return ((u64)hi << 32) | lo;
}
__device__ __forceinline__ int rfl(int x) { return __builtin_amdgcn_readfirstlane(x); }
__device__ __forceinline__ int lanes_below(u64 m) {
  return (int)__builtin_amdgcn_mbcnt_hi((u32)(m >> 32),
             __builtin_amdgcn_mbcnt_lo((u32)m, 0u));
}
__device__ __forceinline__ u32 gm16(u64 m, int lane) {     // own 16-group's bits
  return (u32)(m >> ((lane >> 4) << 4)) & 0xFFFFu;
}

// ---------------- binning: counting-sort each batch's uv into 16x16 cells ----
__global__ __launch_bounds__(1024)
void bin_pts(const float* __restrict__ uv, float2* __restrict__ uvS,
             u16* __restrict__ idxS, u32* __restrict__ cs) {
  __shared__ u32 cnt[NC];
  __shared__ u32 offs[NC];
  __shared__ u32 wtot[4];
  const int bb  = blockIdx.x;
  const int tid = threadIdx.x;

  if (tid < NC) cnt[tid] = 0;
  __syncthreads();

  float2 c4[4];
  int cell[4];
  #pragma unroll
  for (int i = 0; i < 4; ++i) {
    const int p = tid + i * 1024;
    const float2 c = ((const float2*)(uv + (size_t)bb * NM * 2))[p];
    int cx = (int)(c.x * (float)GC); cx = cx > GC - 1 ? GC - 1 : (cx < 0 ? 0 : cx);
    int cy = (int)(c.y * (float)GC); cy = cy > GC - 1 ? GC - 1 : (cy < 0 ? 0 : cy);
    c4[i] = c; cell[i] = cy * GC + cx;
    atomicAdd(&cnt[cell[i]], 1u);
  }
  __syncthreads();

  if (tid < NC) {
    const int lane = tid & 63;
    u32 inc = cnt[tid];
    #pragma unroll
    for (int o = 1; o < 64; o <<= 1) {
      const u32 t = __shfl_up(inc, o, 64);
      if (lane >= o) inc += t;
    }
    offs[tid] = inc;
    if (lane == 63) wtot[tid >> 6] = inc;
  }
  __syncthreads();
  if (tid < NC) {
    const int w = tid >> 6;
    u32 base = 0;
    #pragma unroll
    for (int i = 0; i < 3; ++i) base += (i < w) ? wtot[i] : 0;
    const u32 excl = base + offs[tid] - cnt[tid];
    cs[bb * CSST + tid] = excl;
    offs[tid] = excl;
    if (tid == 0) cs[bb * CSST + NC] = NM;
  }
  __syncthreads();

  #pragma unroll
  for (int i = 0; i < 4; ++i) {
    const int p = tid + i * 1024;
    const u32 pos = atomicAdd(&offs[cell[i]], 1u);
    uvS[(size_t)bb * NM + pos]  = c4[i];
    idxS[(size_t)bb * NM + pos] = (u16)p;
  }
}

// ---------------- main: 4 queries/wave, grid-pruned exact 16-NN + eigen ----
__global__ __launch_bounds__(BLK, 8)
void knn_eig(const float* __restrict__ X, const float* __restrict__ uv,
             const float2* __restrict__ uvS, const u16* __restrict__ idxS,
             const u32* __restrict__ cs, float* __restrict__ out) {
  __shared__ u64 surv[WPB][QPW * 32];        // 8 KB: 32 slots per query

  const int tid  = threadIdx.x;
  const int lane = tid & 63;
  const int sub  = lane & 15;                // lane within 16-group
  const int g4   = lane >> 4;                // query 0..3 within wave
  const int wv   = tid >> 6;
  const int bb   = blockIdx.x >> 7;          // 128 blocks per batch
  const int q    = ((blockIdx.x & 127) << 5) + (wv << 2) + g4;

  const float qu = uv[((size_t)bb * NM + q) * 2];
  const float qv = uv[((size_t)bb * NM + q) * 2 + 1];
  int cxv = (int)(qu * (float)GC); cxv = cxv > GC - 1 ? GC - 1 : (cxv < 0 ? 0 : cxv);
  int cyv = (int)(qv * (float)GC); cyv = cyv > GC - 1 ? GC - 1 : (cyv < 0 ? 0 : cyv);
  const u32* csb = cs + bb * CSST;
  const float2* uvb = uvS + (size_t)bb * NM;
  const u16* idxb = idxS + (size_t)bb * NM;

  float d[SLG];
  #pragma unroll
  for (int t = 0; t < SLG; ++t) d[t] = 1e30f;

  constexpr float TAU1 = 0.0017f;            // ~22 expected survivors
  constexpr float TAU2 = 0.00390625f;        // (1/16)^2 (covered radius, exact fp)

  // ---- h=1 ring (3 rows) per 16-group, fused tau1 count ----
  int rs0, rc0, rs1, rc1, rs2, total, tsw;
  bool ovf;
  int cnt = 0;
  {
    const int x0 = cxv > 0 ? cxv - 1 : 0, x1 = cxv < GC - 1 ? cxv + 1 : GC - 1;
    const int y0 = cyv > 0 ? cyv - 1 : 0, y1 = cyv < GC - 1 ? cyv + 1 : GC - 1;
    rs0 = (int)csb[y0 * GC + x0];
    rc0 = (int)csb[y0 * GC + x1 + 1] - rs0;
    rs1 = (int)csb[(y0 + 1) * GC + x0];
    rc1 = rc0 + (int)csb[(y0 + 1) * GC + x1 + 1] - rs1;
    const bool ok2 = (y0 + 2) <= y1;
    rs2 = (int)csb[ok2 ? ((y0 + 2) * GC + x0) : 0];
    const int re2 = (int)csb[ok2 ? ((y0 + 2) * GC + x1 + 1) : 0];
    total = rc1 + (ok2 ? (re2 - rs2) : 0);
    ovf = total > SLG * 16;                  // ~+4 sigma, routes to cold path
    int ts = (total + 15) >> 4; if (ts > SLG) ts = SLG;
    int m1 = max(ts, __shfl_xor(ts, 16, 64));
    m1 = max(m1, __shfl_xor(m1, 32, 64));
    tsw = rfl(m1);
    #pragma unroll
    for (int t = 0; t < SLG; ++t) {
      if (t >= tsw) break;                   // wave-uniform scalar break
      const int L = t * 16 + sub;
      int addr = rs0 + L;
      if (L >= rc0) addr = rs1 + (L - rc0);
      if (L >= rc1) addr = rs2 + (L - rc1);
      float dd = 1e30f;
      if (L < total) {
        const float2 c = uvb[addr];
        const float dx = __fsub_rn(qu, c.x);
        const float dy = __fsub_rn(qv, c.y);
        dd = __fadd_rn(__fmul_rn(dx, dx), __fmul_rn(dy, dy));
      }
      d[t] = dd;
      cnt += (int)__popc(gm16(__ballot(dd <= TAU1), lane));
    }
    if (ovf) cnt = 0;
  }

  // ---- tau ladder: group-wise escalate tau1 -> tau2 ----
  float hi2 = (cnt < KNN) ? TAU2 : TAU1;
  if (__any(cnt < KNN)) {
    int c2 = 0;
    #pragma unroll
    for (int t = 0; t < SLG; ++t) {
      if (t >= tsw) break;
      c2 += (int)__popc(gm16(__ballot(d[t] <= TAU2), lane));
    }
    if (cnt < KNN && !ovf) cnt = c2;
  }

  // ---- group-wise narrow to <=32 survivors ----
  {
    float lo = (hi2 > TAU1) ? TAU1 : 0.f;    // escalated groups know cnt(tau1)<16
    for (int it = 0; __any(cnt > 32) && it < 40; ++it) {
      const float mid = 0.5f * (lo + hi2);
      int c = 0;
      #pragma unroll
      for (int t = 0; t < SLG; ++t) {
        if (t >= tsw) break;
        c += (int)__popc(gm16(__ballot(cnt > 32 && d[t] <= mid), lane));
      }
      if (cnt > 32) {
        if (!(mid > lo && mid < hi2)) { cnt = 32; }
        else if (c >= KNN) { hi2 = mid; cnt = c; }
        else lo = mid;
      }
    }
  }

  // ---- compact survivors into own 32-slot region ----
  u64* sb = surv[wv];
  {
    int base = 0;
    #pragma unroll
    for (int t = 0; t < SLG; ++t) {
      if (t >= tsw) break;
      const bool p = d[t] <= hi2;
      const u32 mg = gm16(__ballot(p), lane);
      if (p) {
        const int pos = base + (int)__popc(mg & ((1u << sub) - 1u));
        if (pos < 32) {
          const int L = t * 16 + sub;
          int addr = rs0 + L;
          if (L >= rc0) addr = rs1 + (L - rc0);
          if (L >= rc1) addr = rs2 + (L - rc1);
          sb[(g4 << 5) + pos] = ((u64)__float_as_uint(d[t]) << 32) | (u64)idxb[addr];
        }
      }
      base += (int)__popc(mg);
    }
  }

  // ---- cold escalation: serialize needy query onto the full wave ----
  if (__any(cnt < KNN)) {
    #pragma unroll 1
    for (int g = 0; g < QPW; ++g) {
      if (!rfl((__shfl(cnt, g << 4, 64) < KNN) ? 1 : 0)) continue;
      const float gu = __shfl(qu, g << 4, 64);
      const float gv = __shfl(qv, g << 4, 64);
      const int gcx = rfl(__shfl(cxv, g << 4, 64));
      const int gcy = rfl(__shfl(cyv, g << 4, 64));
      float gd[SLC];
      int   ga[SLC];
      float ghi = 0.f;
      int gcnt = 0, gts = 0, gtotal = 0;
      for (int h = 2; h <= 5; ++h) {
        const int x0 = gcx - h < 0 ? 0 : gcx - h, x1 = gcx + h > GC - 1 ? GC - 1 : gcx + h;
        const int y0 = gcy - h < 0 ? 0 : gcy - h, y1 = gcy + h > GC - 1 ? GC - 1 : gcy + h;
        int rstart[7], rcum[7];
        int cum = 0;
        #pragma unroll
        for (int r = 0; r < 7; ++r) {
          const int y = y0 + r;
          const bool ok = (y <= y1);
          const u32 s = csb[ok ? (y * GC + x0) : 0];
          const u32 e = csb[ok ? (y * GC + x1 + 1) : 0];
          rstart[r] = (int)s;
          cum += ok ? (int)(e - s) : 0;
          rcum[r] = cum;
        }
        gtotal = cum;
        int t0 = (gtotal + 63) >> 6; if (t0 > SLC) t0 = SLC;
        gts = rfl(t0);
        const float hv = (float)h * 0.0625f;
        ghi = hv * hv;
        gcnt = 0;
        #pragma unroll
        for (int t = 0; t < SLC; ++t) {
          if (t >= gts) break;
          const int L = t * 64 + lane;
          int addr = rstart[0] + L;
          #pragma unroll
          for (int r = 1; r < 7; ++r)
            if (L >= rcum[r - 1]) addr = rstart[r] + (L - rcum[r - 1]);
          float dd = 1e30f;
          if (L < gtotal) {
            const float2 c = uvb[addr];
            const float dx = __fsub_rn(gu, c.x);
            const float dy = __fsub_rn(gv, c.y);
            dd = __fadd_rn(__fmul_rn(dx, dx), __fmul_rn(dy, dy));
          }
          gd[t] = dd; ga[t] = addr;
          gcnt += (int)__popcll(__ballot(dd <= ghi));
        }
        if (rfl(gcnt) >= KNN) break;
      }
      {
        float lo = 0.f;
        for (int it = 0; rfl(gcnt) > 32 && it < 40; ++it) {
          const float mid = 0.5f * (lo + ghi);
          if (!(mid > lo && mid < ghi)) break;
          int c = 0;
          #pragma unroll
          for (int t = 0; t < SLC; ++t) {
            if (t >= gts) break;
            c += (int)__popcll(__ballot(gd[t] <= mid));
          }
          if (c >= KNN) { ghi = mid; gcnt = c; } else lo = mid;
        }
      }
      int base = 0;
      #pragma unroll
      for (int t = 0; t < SLC; ++t) {
        if (t >= gts) break;
        const bool p = gd[t] <= ghi;
        const u64 m = __ballot(p);
        if (p) {
          const int pos = base + lanes_below(m);
          if (pos < 32)
            sb[(g << 5) + pos] = ((u64)__float_as_uint(gd[t]) << 32) | (u64)idxb[ga[t]];
        }
        base += (int)__popcll(m);
      }
      if (g4 == g) cnt = gcnt < 32 ? gcnt : 32;
    }
  }

  // ---- top-16 selection: sort v0 asc, v1 desc (parallel chains), min-prune ----
  const int S = cnt < 32 ? cnt : 32;
  const int sbase = g4 << 5;
  u64 v0 = (sub < S) ? sb[sbase + sub] : ~0ull;
  u64 v1 = (16 + sub < S) ? sb[sbase + 16 + sub] : ~0ull;
  #pragma unroll
  for (int k = 2; k <= 16; k <<= 1) {
    #pragma unroll
    for (int j = k >> 1; j > 0; j >>= 1) {
      const u64 o0 = shflx64(v0, j);
      const u64 o1 = shflx64(v1, j);
      const bool up = ((sub & k) == 0);      // k=16: always true -> v0 asc, v1 desc
      const bool j0 = ((sub & j) == 0);
      const bool km0 = (j0 == up);
      const bool km1 = (j0 != up);
      v0 = ((v0 < o0) == km0) ? v0 : o0;
      v1 = ((v1 < o1) == km1) ? v1 : o1;
    }
  }
  const u64 v = (v0 < v1) ? v0 : v1;         // bitonic prune: exact top-16 set

  // ---- gather X (one neighbor per lane), reduce 9 moments over 16 lanes ----
  const int idx = (int)(u32)v & 0xFFF;
  const float* Xp = X + ((size_t)bb * NM + idx) * 3;
  const float x = Xp[0], y = Xp[1], z = Xp[2];
  float sx = x, sy = y, sz = z;
  float sxx = x * x, sxy = x * y, sxz = x * z;
  float syy = y * y, syz = y * z, szz = z * z;
  #pragma unroll
  for (int o = 8; o > 0; o >>= 1) {
    sx  += __shfl_xor(sx,  o, 64);  sy  += __shfl_xor(sy,  o, 64);
    sz  += __shfl_xor(sz,  o, 64);  sxx += __shfl_xor(sxx, o, 64);
    sxy += __shfl_xor(sxy, o, 64);  sxz += __shfl_xor(sxz, o, 64);
    syy += __shfl_xor(syy, o, 64);  syz += __shfl_xor(syz, o, 64);
    szz += __shfl_xor(szz, o, 64);
  }

  // ---- covariance + closed-form symmetric 3x3 eigenvalues ----
  const float mx = sx * 0.0625f, my = sy * 0.0625f, mz = sz * 0.0625f;
  const float c00 = sxx - 16.f * mx * mx;
  const float c11 = syy - 16.f * my * my;
  const float c22 = szz - 16.f * mz * mz;
  const float c01 = sxy - 16.f * mx * my;
  const float c02 = sxz - 16.f * mx * mz;
  const float c12 = syz - 16.f * my * mz;

  const float tr = c00 + c11 + c22;
  const float q3 = tr * (1.f / 3.f);
  const float b0 = c00 - q3, b1 = c11 - q3, b2 = c22 - q3;
  const float p2 = b0 * b0 + b1 * b1 + b2 * b2 +
                   2.f * (c01 * c01 + c02 * c02 + c12 * c12);
  float e0, e1, e2;
  if (p2 < 1e-30f) {
    e0 = e1 = e2 = q3;
  } else {
    const float p  = sqrtf(p2 * (1.f / 6.f));
    const float ip = 1.f / p;
    const float m00 = b0 * ip, m11 = b1 * ip, m22 = b2 * ip;
    const float m01 = c01 * ip, m02 = c02 * ip, m12 = c12 * ip;
    const float det = m00 * (m11 * m22 - m12 * m12)
                    - m01 * (m01 * m22 - m12 * m02)
                    + m02 * (m01 * m12 - m11 * m02);
    float r = 0.5f * det;
    r = fminf(1.f, fmaxf(-1.f, r));
    const float phi = acosf(r) * (1.f / 3.f);
    float sphi, cphi;
    __sincosf(phi, &sphi, &cphi);
    e0 = q3 + 2.f * p * cphi;                                        // largest
    e2 = q3 + 2.f * p * (-0.5f * cphi - 0.8660254037844386f * sphi); // smallest
    e1 = tr - e0 - e2;
  }

  if (sub == 0) {
    float* op = out + ((size_t)bb * NM + q) * 3;
    op[0] = e0; op[1] = e1; op[2] = e2;
  }
}

extern "C" void kernel_launch(void* const* d_in, const int* in_sizes, int n_in,
                              void* d_out, int out_size, void* d_ws, size_t ws_size,
                              hipStream_t stream) {
  const float* X  = (const float*)d_in[0];
  const float* uv = (const float*)d_in[1];
  float* out = (float*)d_out;
  char* ws = (char*)d_ws;
  float2* uvS = (float2*)(ws + WS_UVS);
  u16*    idxS = (u16*)(ws + WS_IDX);
  u32*    csP  = (u32*)(ws + WS_CS);

  bin_pts<<<dim3(NB), dim3(1024), 0, stream>>>(uv, uvS, idxS, csP);
  knn_eig<<<dim3(NB * NM / QPB), dim3(BLK), 0, stream>>>(X, uv, uvS, idxS, csP, out);
}